// Round 4
// baseline (6270.438 us; speedup 1.0000x reference)
//
#include <hip/hip_runtime.h>
#include <hip/hip_bf16.h>

typedef __hip_bfloat16 bf16;
#define DEV __device__ __forceinline__

DEV float b2f(bf16 x) { return __bfloat162float(x); }
DEV bf16  f2b(float x) { return __float2bfloat16(x); }

static constexpr int B = 8, C = 128, S = 16;
static constexpr int L = S * S * S;                 // 4096
static constexpr size_t BL   = (size_t)B * L;       // 32768 tokens
static constexpr size_t VOLE = BL * C;              // 4,194,304 elements / volume

// ---- canonical f32 weight region (element offsets) ----
static constexpr size_t W_PW1  = 0;        // 163840
static constexpr size_t W_PW1B = 163840;
static constexpr size_t W_LN1G = 165120;
static constexpr size_t W_LN1B = 166400;
static constexpr size_t W_DWW  = 167680;   // 34560
static constexpr size_t W_DWB  = 202240;
static constexpr size_t W_LN2G = 203520;
static constexpr size_t W_LN2B = 204800;
static constexpr size_t W_PW2  = 206080;   // 163840
static constexpr size_t W_PW2B = 369920;
static constexpr size_t W_LN3G = 371200;
static constexpr size_t W_LN3B = 372480;   // end 373760 elements (1.43 MB f32)

// ---- workspace layout (bytes). Total ~84 MB, all-f32 activations. ----
static constexpr size_t OFF_FLAG = 0;                       // int flag (256 B reserved)
static constexpr size_t OFF_WTS  = 256;                     // f32 canonical weights
static constexpr size_t OFF_A    = 2u << 20;                // f32 [B,L,C] (transpose out, dw out)
static constexpr size_t OFF_BB   = OFF_A  + VOLE * 4;       // f32 [B,L,C] (pw1 out)
static constexpr size_t OFF_Q    = OFF_BB + VOLE * 4;       // f32 [B,L,C] q stream
static constexpr size_t OFF_KV   = OFF_Q  + VOLE * 4;       // f32 [B,L,C] per-modality K/V
static constexpr size_t OFF_X    = OFF_KV + VOLE * 4;       // f32 [B,L,C] attention out accum
static constexpr size_t OFF_ATT  = OFF_X  + VOLE * 4;       // f32 [B,128,512]
// end = OFF_ATT + 2 MB = 88,080,384 bytes

DEV float gelu(float x) { return 0.5f * x * (1.f + erff(x * 0.70710678118654752f)); }

// LayerNorm stats across a 128-thread block (2 waves). red = shared float[4].
DEV void ln_stats_128(float v, int tid, float* red, float& mean, float& rstd) {
  float s = v, q = v * v;
  #pragma unroll
  for (int off = 32; off; off >>= 1) { s += __shfl_down(s, off); q += __shfl_down(q, off); }
  if ((tid & 63) == 0) { red[(tid >> 6) * 2] = s; red[(tid >> 6) * 2 + 1] = q; }
  __syncthreads();
  float S_ = red[0] + red[2], Q_ = red[1] + red[3];
  mean = S_ * (1.f / 128.f);
  float var = fmaxf(Q_ * (1.f / 128.f) - mean * mean, 0.f);
  rstd = rsqrtf(var + 1e-6f);
}

// ---- dtype sniffer: flag=1 if inputs are bf16, 0 if f32. 1 block x 64 threads. ----
__global__ void k_sniff(const unsigned* __restrict__ q, int* __restrict__ flag) {
  int t = threadIdx.x;
  unsigned u = q[t];
  int good = 0;
  #pragma unroll
  for (int h = 0; h < 2; ++h) {
    unsigned hb = (h ? (u & 0xffff0000u) : (u << 16));
    float v = __uint_as_float(hb);
    float a = fabsf(v);
    if (v == 0.f || (a > 1e-20f && a < 100.f)) good++;
  }
  #pragma unroll
  for (int off = 32; off; off >>= 1) good += __shfl_down(good, off);
  if (t == 0) *flag = (good >= 112) ? 1 : 0;
}

// ---- convert one weight array to canonical f32 (lossless if src is bf16) ----
__global__ void k_cvt(const void* __restrict__ src, float* __restrict__ dst, int n,
                      const int* __restrict__ flagp) {
  int i = blockIdx.x * 256 + threadIdx.x;
  if (i >= n) return;
  if (*flagp) dst[i] = b2f(((const bf16*)src)[i]);
  else        dst[i] = ((const float*)src)[i];
}

// [B,C,L] -> [B,L,C] for ONE volume, LDS-tiled, dtype-branched loads, f32 out.
__global__ __launch_bounds__(256) void k_transpose(const void* __restrict__ sv,
                                                   float* __restrict__ d,
                                                   const int* __restrict__ flagp) {
  __shared__ float t[32][33];
  bool isb = (*flagp != 0);
  int b = blockIdx.z;
  int c0 = blockIdx.y * 32, l0 = blockIdx.x * 32;
  int tid = threadIdx.x;
  int lr = tid & 31, cr = tid >> 5;     // read: 8 c-rows x 32 l per pass
  #pragma unroll
  for (int i = 0; i < 4; ++i) {
    size_t si = ((size_t)b * C + (c0 + cr + i * 8)) * L + l0 + lr;
    t[cr + i * 8][lr] = isb ? b2f(((const bf16*)sv)[si]) : ((const float*)sv)[si];
  }
  __syncthreads();
  int cw = tid & 31, lw = tid >> 5;     // write: 8 l-rows x 32 c per pass
  #pragma unroll
  for (int i = 0; i < 4; ++i) {
    int l = l0 + lw + i * 8;
    d[((size_t)b * L + l) * C + c0 + cw] = t[cw][lw + i * 8];
  }
}

// pointwise conv (C->C) + bias + LN + optional GELU. One token per 128-thread block. All f32.
template <bool DOGELU>
__global__ __launch_bounds__(128) void k_pw_ln(
    const float* __restrict__ in, float* __restrict__ out,
    const float* __restrict__ W, const float* __restrict__ bias,
    const float* __restrict__ gam, const float* __restrict__ bet, int blk) {
  __shared__ __align__(16) float xs[128];
  __shared__ float red[4];
  size_t tok = blockIdx.x;
  int o = threadIdx.x;
  xs[o] = in[tok * 128 + o];
  __syncthreads();
  const float* wr = W + (((size_t)blk * 128 + o) << 7);
  float acc = bias[blk * 128 + o];
  #pragma unroll
  for (int c0 = 0; c0 < 128; c0 += 8) {
    float4 w0 = *(const float4*)(wr + c0);
    float4 w1 = *(const float4*)(wr + c0 + 4);
    float4 x0 = *(const float4*)&xs[c0];
    float4 x1 = *(const float4*)&xs[c0 + 4];
    acc += w0.x * x0.x + w0.y * x0.y + w0.z * x0.z + w0.w * x0.w
         + w1.x * x1.x + w1.y * x1.y + w1.z * x1.z + w1.w * x1.w;
  }
  float mean, rstd;
  ln_stats_128(acc, o, red, mean, rstd);
  float yv = (acc - mean) * rstd * gam[blk * 128 + o] + bet[blk * 128 + o];
  if (DOGELU) yv = gelu(yv);
  out[tok * 128 + o] = yv;
}

// depthwise 3x3x3 'SAME' + bias + LN + GELU. One token per 128-thread block (thread = channel).
__global__ __launch_bounds__(128) void k_dw_ln(
    const float* __restrict__ in, float* __restrict__ out,
    const float* __restrict__ W, const float* __restrict__ bias,
    const float* __restrict__ gam, const float* __restrict__ bet, int blk) {
  __shared__ float red[4];
  int c = threadIdx.x;
  size_t tok = blockIdx.x;
  int b = (int)(tok >> 12);
  int l = (int)(tok & 4095);
  int z = l >> 8, y = (l >> 4) & 15, x = l & 15;
  const float* wc = W + ((size_t)blk * 128 + c) * 27;
  float wreg[27];
  #pragma unroll
  for (int i = 0; i < 27; ++i) wreg[i] = wc[i];
  const float* base = in + (((size_t)b) << 12) * 128;
  float acc = bias[blk * 128 + c];
  #pragma unroll
  for (int kd = 0; kd < 3; ++kd) {
    int zz = z + kd - 1;
    if ((unsigned)zz > 15u) continue;          // zero padding (uniform across block)
    #pragma unroll
    for (int kh = 0; kh < 3; ++kh) {
      int yy = y + kh - 1;
      if ((unsigned)yy > 15u) continue;
      #pragma unroll
      for (int kw = 0; kw < 3; ++kw) {
        int xx = x + kw - 1;
        if ((unsigned)xx > 15u) continue;
        int ll = (zz << 8) | (yy << 4) | xx;
        acc += wreg[kd * 9 + kh * 3 + kw] * base[(size_t)ll * 128 + c];
      }
    }
  }
  float mean, rstd;
  ln_stats_128(acc, c, red, mean, rstd);
  float yv = (acc - mean) * rstd * gam[blk * 128 + c] + bet[blk * 128 + c];
  out[tok * 128 + c] = gelu(yv);
}

// attn[b,c,ki*128+k] += sum_l q[b,l,c]*K[b,l,k]   (l-split across blocks, atomic accumulate)
__global__ __launch_bounds__(256) void k_qk(
    const float* __restrict__ qtok, const float* __restrict__ ktok,
    float* __restrict__ attn, int ki) {
  __shared__ __align__(16) float qs[32][128];
  __shared__ __align__(16) float ks[32][128];
  int ls = blockIdx.x, b = blockIdx.y;
  const float* qb = qtok + (size_t)b * ((size_t)L * C);
  const float* kb = ktok + (size_t)b * ((size_t)L * C);
  int t = threadIdx.x;
  int tc = t & 15, tk = t >> 4;
  float acc[8][8];
  #pragma unroll
  for (int i = 0; i < 8; ++i)
    #pragma unroll
    for (int j = 0; j < 8; ++j) acc[i][j] = 0.f;
  for (int l0 = ls * 256; l0 < ls * 256 + 256; l0 += 32) {
    #pragma unroll
    for (int p = 0; p < 4; ++p) {
      int idx = p * 256 + t;
      int r = idx >> 5, c4 = (idx & 31) * 4;
      *(float4*)&qs[r][c4] = *(const float4*)&qb[(size_t)(l0 + r) * 128 + c4];
      *(float4*)&ks[r][c4] = *(const float4*)&kb[(size_t)(l0 + r) * 128 + c4];
    }
    __syncthreads();
    #pragma unroll 8
    for (int l = 0; l < 32; ++l) {
      float4 q0 = *(const float4*)&qs[l][tc * 8];
      float4 q1 = *(const float4*)&qs[l][tc * 8 + 4];
      float4 k0 = *(const float4*)&ks[l][tk * 8];
      float4 k1 = *(const float4*)&ks[l][tk * 8 + 4];
      float a[8]  = {q0.x, q0.y, q0.z, q0.w, q1.x, q1.y, q1.z, q1.w};
      float bb[8] = {k0.x, k0.y, k0.z, k0.w, k1.x, k1.y, k1.z, k1.w};
      #pragma unroll
      for (int i = 0; i < 8; ++i)
        #pragma unroll
        for (int j = 0; j < 8; ++j) acc[i][j] += a[i] * bb[j];
    }
    __syncthreads();
  }
  #pragma unroll
  for (int i = 0; i < 8; ++i) {
    int cc = tc * 8 + i;
    #pragma unroll
    for (int j = 0; j < 8; ++j) {
      int kk = ki * 128 + tk * 8 + j;
      atomicAdd(&attn[((size_t)b * 128 + cc) * 512 + kk], acc[i][j]);
    }
  }
}

// masked softmax over k=512 per (b,c) row; scale = L^-0.5 = 1/64.
__global__ __launch_bounds__(128) void k_sm(float* __restrict__ attn, const int* __restrict__ mask) {
  __shared__ float rm[2], rs[2];
  int b = blockIdx.x >> 7;
  float* row = attn + (size_t)blockIdx.x * 512;
  int t = threadIdx.x;
  float v[4];
  #pragma unroll
  for (int j = 0; j < 4; ++j) {
    int k = t + j * 128;
    v[j] = (mask[b * 4 + j] > 0) ? row[k] * 0.015625f : -1e30f;
  }
  float m = fmaxf(fmaxf(v[0], v[1]), fmaxf(v[2], v[3]));
  #pragma unroll
  for (int off = 32; off; off >>= 1) m = fmaxf(m, __shfl_down(m, off));
  if ((t & 63) == 0) rm[t >> 6] = m;
  __syncthreads();
  m = fmaxf(rm[0], rm[1]);
  float e[4], s = 0.f;
  #pragma unroll
  for (int j = 0; j < 4; ++j) { e[j] = expf(v[j] - m); s += e[j]; }
  #pragma unroll
  for (int off = 32; off; off >>= 1) s += __shfl_down(s, off);
  if ((t & 63) == 0) rs[t >> 6] = s;
  __syncthreads();
  float inv = 1.f / (rs[0] + rs[1]);
  #pragma unroll
  for (int j = 0; j < 4; ++j) row[t + j * 128] = e[j] * inv;
}

// x[b,l,c] += sum_{k in ki-block} P[b,c,ki*128+k] * V[b,l,k]. Block = (ltile 32, b), thread = c.
__global__ __launch_bounds__(128) void k_av(
    const float* __restrict__ attn, const float* __restrict__ vtok,
    float* __restrict__ xout, int ki) {
  __shared__ __align__(16) float vs[32][128];
  int l0 = blockIdx.x * 32, b = blockIdx.y;
  int t = threadIdx.x;
  const float* vb = vtok + ((size_t)b * L + l0) * 128;
  #pragma unroll
  for (int p = 0; p < 8; ++p) {
    int idx = p * 128 + t;
    int r = idx >> 5, c4 = (idx & 31) * 4;
    *(float4*)&vs[r][c4] = *(const float4*)&vb[(size_t)r * 128 + c4];
  }
  __syncthreads();
  const float* prow = attn + ((size_t)b * 128 + t) * 512 + ki * 128;
  float acc[32];
  #pragma unroll
  for (int i = 0; i < 32; ++i) acc[i] = 0.f;
  for (int k0 = 0; k0 < 128; k0 += 32) {
    float a[32];
    #pragma unroll
    for (int j = 0; j < 8; ++j) *(float4*)&a[j * 4] = *(const float4*)&prow[k0 + j * 4];
    #pragma unroll 8
    for (int tt = 0; tt < 32; ++tt) {
      #pragma unroll
      for (int j = 0; j < 32; ++j) acc[tt] += vs[tt][k0 + j] * a[j];
    }
  }
  #pragma unroll
  for (int tt = 0; tt < 32; ++tt)
    xout[(((size_t)b << 12) + l0 + tt) * 128 + t] += acc[tt];
}

// out[b,c,l] = query[b,c,l] + x9[b,l,c]  (dtype-branched query load + out store)
__global__ __launch_bounds__(256) void k_final(
    const void* __restrict__ qv, const float* __restrict__ xin, void* __restrict__ outv,
    const int* __restrict__ flagp) {
  __shared__ float tl[32][33];
  bool isb = (*flagp != 0);
  int l0 = blockIdx.x * 32, c0 = blockIdx.y * 32, b = blockIdx.z;
  int t = threadIdx.x;
  int cc = t & 31, lr = t >> 5;
  #pragma unroll
  for (int p = 0; p < 4; ++p) {
    int l = l0 + lr + p * 8;
    tl[lr + p * 8][cc] = xin[((((size_t)b) << 12) + l) * 128 + c0 + cc];
  }
  __syncthreads();
  int lw = t & 31, cr = t >> 5;
  #pragma unroll
  for (int p = 0; p < 4; ++p) {
    int c = c0 + cr + p * 8;
    size_t idx = (((size_t)b * 128 + c) << 12) + l0 + lw;
    float qf = isb ? b2f(((const bf16*)qv)[idx]) : ((const float*)qv)[idx];
    float r = qf + tl[lw][cr + p * 8];
    if (isb) ((bf16*)outv)[idx] = f2b(r);
    else     ((float*)outv)[idx] = r;
  }
}

extern "C" void kernel_launch(void* const* d_in, const int* in_sizes, int n_in,
                              void* d_out, int out_size, void* d_ws, size_t ws_size,
                              hipStream_t stream) {
  const void* vols[5] = {d_in[0], d_in[1], d_in[2], d_in[3], d_in[4]};
  const int* mask = (const int*)d_in[5];

  char* ws = (char*)d_ws;
  int*   flag  = (int*)(ws + OFF_FLAG);
  float* wts   = (float*)(ws + OFF_WTS);
  float* bufA  = (float*)(ws + OFF_A);
  float* bufB  = (float*)(ws + OFF_BB);
  float* qtok  = (float*)(ws + OFF_Q);
  float* kv    = (float*)(ws + OFF_KV);
  float* xattn = (float*)(ws + OFF_X);
  float* attn  = (float*)(ws + OFF_ATT);

  // 1. dtype sniff
  k_sniff<<<1, 64, 0, stream>>>((const unsigned*)d_in[0], flag);

  // 2. canonicalize weights to f32 in ws
  const size_t woff[12] = {W_PW1, W_PW1B, W_LN1G, W_LN1B, W_DWW, W_DWB,
                           W_LN2G, W_LN2B, W_PW2, W_PW2B, W_LN3G, W_LN3B};
  for (int i = 0; i < 12; ++i) {
    int n = in_sizes[6 + i];
    k_cvt<<<(n + 255) / 256, 256, 0, stream>>>(d_in[6 + i], wts + woff[i], n, flag);
  }
  const float *pw1_w = wts + W_PW1, *pw1_b = wts + W_PW1B, *ln1_g = wts + W_LN1G, *ln1_b = wts + W_LN1B;
  const float *dw_w = wts + W_DWW, *dw_b = wts + W_DWB, *ln2_g = wts + W_LN2G, *ln2_b = wts + W_LN2B;
  const float *pw2_w = wts + W_PW2, *pw2_b = wts + W_PW2B, *ln3_g = wts + W_LN3G, *ln3_b = wts + W_LN3B;

  dim3 tg(L / 32, 4, 8);
  // transpose->A; pw1 A->B; dw B->A; pw2 A->dst
  auto run_block = [&](const void* src_vol, int blk, float* dst) {
    k_transpose<<<tg, 256, 0, stream>>>(src_vol, bufA, flag);
    k_pw_ln<true><<<(int)BL, 128, 0, stream>>>(bufA, bufB, pw1_w, pw1_b, ln1_g, ln1_b, blk);
    k_dw_ln<<<(int)BL, 128, 0, stream>>>(bufB, bufA, dw_w, dw_b, ln2_g, ln2_b, blk);
    k_pw_ln<false><<<(int)BL, 128, 0, stream>>>(bufA, dst, pw2_w, pw2_b, ln3_g, ln3_b, blk);
  };

  // q stream (block 0)
  run_block(vols[0], 0, qtok);

  hipMemsetAsync(attn, 0, (size_t)B * 128 * 512 * 4, stream);
  hipMemsetAsync(xattn, 0, VOLE * 4, stream);

  // K streams (blocks 1-4), accumulate attn
  for (int m = 1; m <= 4; ++m) {
    run_block(vols[m], m, kv);
    k_qk<<<dim3(16, 8), 256, 0, stream>>>(qtok, kv, attn, m - 1);
  }

  k_sm<<<(int)(B * 128), 128, 0, stream>>>(attn, mask);

  // V streams (blocks 5-8), accumulate x
  for (int m = 1; m <= 4; ++m) {
    run_block(vols[m], 4 + m, kv);
    k_av<<<dim3(L / 32, B), 128, 0, stream>>>(attn, kv, xattn, m - 1);
  }

  // block 9 on attention output, then residual + transpose back
  k_pw_ln<true><<<(int)BL, 128, 0, stream>>>(xattn, bufB, pw1_w, pw1_b, ln1_g, ln1_b, 9);
  k_dw_ln<<<(int)BL, 128, 0, stream>>>(bufB, bufA, dw_w, dw_b, ln2_g, ln2_b, 9);
  k_pw_ln<false><<<(int)BL, 128, 0, stream>>>(bufA, kv, pw2_w, pw2_b, ln3_g, ln3_b, 9);
  k_final<<<dim3(L / 32, 4, 8), 256, 0, stream>>>(vols[0], kv, d_out, flag);
}

// Round 5
// 2641.050 us; speedup vs baseline: 2.3742x; 2.3742x over previous
//
#include <hip/hip_runtime.h>
#include <hip/hip_bf16.h>

typedef __hip_bfloat16 bf16;
#define DEV __device__ __forceinline__

DEV float b2f(bf16 x) { return __bfloat162float(x); }
DEV bf16  f2b(float x) { return __float2bfloat16(x); }

static constexpr int B = 8, C = 128, S = 16;
static constexpr int L = S * S * S;                 // 4096
static constexpr size_t BL   = (size_t)B * L;       // 32768 tokens
static constexpr size_t VOLE = BL * C;              // 4,194,304 elements / volume

// ---- canonical f32 weight region (element offsets) ----
static constexpr size_t W_PW1  = 0;
static constexpr size_t W_PW1B = 163840;
static constexpr size_t W_LN1G = 165120;
static constexpr size_t W_LN1B = 166400;
static constexpr size_t W_DWW  = 167680;
static constexpr size_t W_DWB  = 202240;
static constexpr size_t W_LN2G = 203520;
static constexpr size_t W_LN2B = 204800;
static constexpr size_t W_PW2  = 206080;
static constexpr size_t W_PW2B = 369920;
static constexpr size_t W_LN3G = 371200;
static constexpr size_t W_LN3B = 372480;

// ---- workspace layout (bytes). ~88 MB, all-f32 activations. ----
static constexpr size_t OFF_FLAG = 0;
static constexpr size_t OFF_WTS  = 256;
static constexpr size_t OFF_A    = 2u << 20;
static constexpr size_t OFF_BB   = OFF_A  + VOLE * 4;
static constexpr size_t OFF_Q    = OFF_BB + VOLE * 4;
static constexpr size_t OFF_KV   = OFF_Q  + VOLE * 4;
static constexpr size_t OFF_X    = OFF_KV + VOLE * 4;
static constexpr size_t OFF_ATT  = OFF_X  + VOLE * 4;

DEV float gelu(float x) { return 0.5f * x * (1.f + erff(x * 0.70710678118654752f)); }

// ---- dtype sniffer: flag=1 if inputs are bf16, 0 if f32. ----
__global__ void k_sniff(const unsigned* __restrict__ q, int* __restrict__ flag) {
  int t = threadIdx.x;
  unsigned u = q[t];
  int good = 0;
  #pragma unroll
  for (int h = 0; h < 2; ++h) {
    unsigned hb = (h ? (u & 0xffff0000u) : (u << 16));
    float v = __uint_as_float(hb);
    float a = fabsf(v);
    if (v == 0.f || (a > 1e-20f && a < 100.f)) good++;
  }
  #pragma unroll
  for (int off = 32; off; off >>= 1) good += __shfl_down(good, off);
  if (t == 0) *flag = (good >= 112) ? 1 : 0;
}

__global__ void k_cvt(const void* __restrict__ src, float* __restrict__ dst, int n,
                      const int* __restrict__ flagp) {
  int i = blockIdx.x * 256 + threadIdx.x;
  if (i >= n) return;
  if (*flagp) dst[i] = b2f(((const bf16*)src)[i]);
  else        dst[i] = ((const float*)src)[i];
}

// [B,C,L] -> [B,L,C] for ONE volume, LDS-tiled, dtype-branched loads, f32 out.
__global__ __launch_bounds__(256) void k_transpose(const void* __restrict__ sv,
                                                   float* __restrict__ d,
                                                   const int* __restrict__ flagp) {
  __shared__ float t[32][33];
  bool isb = (*flagp != 0);
  int b = blockIdx.z;
  int c0 = blockIdx.y * 32, l0 = blockIdx.x * 32;
  int tid = threadIdx.x;
  int lr = tid & 31, cr = tid >> 5;
  #pragma unroll
  for (int i = 0; i < 4; ++i) {
    size_t si = ((size_t)b * C + (c0 + cr + i * 8)) * L + l0 + lr;
    t[cr + i * 8][lr] = isb ? b2f(((const bf16*)sv)[si]) : ((const float*)sv)[si];
  }
  __syncthreads();
  int cw = tid & 31, lw = tid >> 5;
  #pragma unroll
  for (int i = 0; i < 4; ++i) {
    int l = l0 + lw + i * 8;
    d[((size_t)b * L + l) * C + c0 + cw] = t[cw][lw + i * 8];
  }
}

// ---- pointwise conv as tiled GEMM + fused bias+LN(+GELU). ----
// Block: 256 thr, tile 128 tokens x 128 outputs, K=128. LDS: xs 64KB + wt 64KB.
template <bool DOGELU>
__global__ __launch_bounds__(256) void k_pw_gemm(
    const float* __restrict__ in, float* __restrict__ out,
    const float* __restrict__ W, const float* __restrict__ bias,
    const float* __restrict__ gam, const float* __restrict__ bet, int blk) {
  __shared__ __align__(16) float xs[128][128];   // [token][k], reused as y[token][o]
  __shared__ __align__(16) float wt[128][128];   // [k][o] = W[o][k]
  int t = threadIdx.x;
  size_t tok0 = (size_t)blockIdx.x * 128;
  const float* Wb = W + ((size_t)blk << 14);
  // stage W transposed; lanes span o -> LDS write banks o%32 (2-way max, free)
  #pragma unroll
  for (int p = 0; p < 16; ++p) {
    int idx = p * 256 + t;       // 4096 float4 = 128x128
    int o = idx & 127, q = idx >> 7;
    float4 w = *(const float4*)(Wb + (size_t)o * 128 + q * 4);
    wt[q * 4 + 0][o] = w.x;
    wt[q * 4 + 1][o] = w.y;
    wt[q * 4 + 2][o] = w.z;
    wt[q * 4 + 3][o] = w.w;
  }
  // stage x tile, coalesced
  #pragma unroll
  for (int p = 0; p < 16; ++p) {
    int idx = p * 256 + t;
    int m = idx >> 5, q = idx & 31;
    *(float4*)&xs[m][q * 4] = *(const float4*)(in + (tok0 + m) * 128 + q * 4);
  }
  __syncthreads();
  int tx = t & 15, ty = t >> 4;
  int o0 = tx * 8, m0 = ty * 8;
  float acc[8][8];
  #pragma unroll
  for (int i = 0; i < 8; ++i)
    #pragma unroll
    for (int j = 0; j < 8; ++j) acc[i][j] = 0.f;
  #pragma unroll 4
  for (int k = 0; k < 128; ++k) {
    float a[8];
    #pragma unroll
    for (int i = 0; i < 8; ++i) a[i] = xs[m0 + i][k];
    float4 b0 = *(const float4*)&wt[k][o0];
    float4 b1 = *(const float4*)&wt[k][o0 + 4];
    float bb[8] = {b0.x, b0.y, b0.z, b0.w, b1.x, b1.y, b1.z, b1.w};
    #pragma unroll
    for (int i = 0; i < 8; ++i)
      #pragma unroll
      for (int j = 0; j < 8; ++j) acc[i][j] += a[i] * bb[j];
  }
  // bias, then park y in xs
  float bl[8];
  #pragma unroll
  for (int j = 0; j < 8; ++j) bl[j] = bias[blk * 128 + o0 + j];
  __syncthreads();
  #pragma unroll
  for (int i = 0; i < 8; ++i) {
    float4 y0 = {acc[i][0] + bl[0], acc[i][1] + bl[1], acc[i][2] + bl[2], acc[i][3] + bl[3]};
    float4 y1 = {acc[i][4] + bl[4], acc[i][5] + bl[5], acc[i][6] + bl[6], acc[i][7] + bl[7]};
    *(float4*)&xs[m0 + i][o0] = y0;
    *(float4*)&xs[m0 + i][o0 + 4] = y1;
  }
  __syncthreads();
  // LN: thread -> (token m = t>>1, half = t&1 covering 64 channels)
  int m = t >> 1, half = t & 1;
  float s = 0.f, q2 = 0.f;
  #pragma unroll
  for (int jj = 0; jj < 16; ++jj) {
    float4 v = *(const float4*)&xs[m][half * 64 + jj * 4];
    s  += v.x + v.y + v.z + v.w;
    q2 += v.x * v.x + v.y * v.y + v.z * v.z + v.w * v.w;
  }
  s  += __shfl_xor(s, 1);
  q2 += __shfl_xor(q2, 1);
  float mean = s * (1.f / 128.f);
  float var = fmaxf(q2 * (1.f / 128.f) - mean * mean, 0.f);
  float rstd = rsqrtf(var + 1e-6f);
  #pragma unroll
  for (int jj = 0; jj < 16; ++jj) {
    int c = half * 64 + jj * 4;
    float4 v = *(const float4*)&xs[m][c];
    float4 g = *(const float4*)(gam + blk * 128 + c);
    float4 e = *(const float4*)(bet + blk * 128 + c);
    float4 r;
    r.x = (v.x - mean) * rstd * g.x + e.x;
    r.y = (v.y - mean) * rstd * g.y + e.y;
    r.z = (v.z - mean) * rstd * g.z + e.z;
    r.w = (v.w - mean) * rstd * g.w + e.w;
    if (DOGELU) { r.x = gelu(r.x); r.y = gelu(r.y); r.z = gelu(r.z); r.w = gelu(r.w); }
    *(float4*)(out + (tok0 + m) * 128 + c) = r;
  }
}

// ---- depthwise 3x3x3 + bias + LN + GELU, z-column blocks. ----
// Block: 128 thr = (q=c/4: 32) x (zg: 4). Grid: b*256 + y*16 + x (2048 blocks).
__global__ __launch_bounds__(128) void k_dw_ln(
    const float* __restrict__ in, float* __restrict__ out,
    const float* __restrict__ W, const float* __restrict__ bias,
    const float* __restrict__ gam, const float* __restrict__ bet, int blk) {
  __shared__ __align__(16) float ls[9][16][128];   // 73,728 B
  __shared__ __align__(16) float dww[27][128];     // 13,824 B
  int t = threadIdx.x;
  int xg = blockIdx.x & 15, yg = (blockIdx.x >> 4) & 15, b = blockIdx.x >> 8;
  const float* base = in + (((size_t)b) << 12) * 128;
  const float* Wb = W + (size_t)blk * 3456;
  // stage dw taps transposed [tap][c] (writes bank=c%32: conflict-free)
  #pragma unroll
  for (int i = 0; i < 27; ++i) dww[i][t] = Wb[t * 27 + i];
  // stage 3x3 neighborhood of z-columns
  {
    int c4 = (t & 31) * 4, z0 = (t >> 5) * 4;
    for (int col = 0; col < 9; ++col) {
      int yy = yg + col / 3 - 1, xx = xg + col % 3 - 1;
      bool ok = ((unsigned)yy < 16u) && ((unsigned)xx < 16u);
      #pragma unroll
      for (int w = 0; w < 4; ++w) {
        int z = z0 + w;
        float4 v = {0.f, 0.f, 0.f, 0.f};
        if (ok) v = *(const float4*)(base + ((size_t)((z << 8) | (yy << 4) | xx)) * 128 + c4);
        *(float4*)&ls[col][z][c4] = v;
      }
    }
  }
  __syncthreads();
  int q = t & 31, zg = t >> 5;
  int c0 = q * 4;
  float4 bias4 = *(const float4*)(bias + blk * 128 + c0);
  float acc[4][4];
  #pragma unroll
  for (int z4 = 0; z4 < 4; ++z4) {
    acc[z4][0] = bias4.x; acc[z4][1] = bias4.y; acc[z4][2] = bias4.z; acc[z4][3] = bias4.w;
  }
  #pragma unroll
  for (int ky = 0; ky < 3; ++ky) {
    #pragma unroll
    for (int kx = 0; kx < 3; ++kx) {
      int col = ky * 3 + kx;
      float4 cv[6];
      #pragma unroll
      for (int zz = 0; zz < 6; ++zz) {
        int z = zg * 4 + zz - 1;
        if ((unsigned)z < 16u) cv[zz] = *(const float4*)&ls[col][z][c0];
        else                   cv[zz] = {0.f, 0.f, 0.f, 0.f};
      }
      #pragma unroll
      for (int kz = 0; kz < 3; ++kz) {
        float4 w4 = *(const float4*)&dww[kz * 9 + col][c0];
        #pragma unroll
        for (int z4 = 0; z4 < 4; ++z4) {
          float4 v = cv[z4 + kz];
          acc[z4][0] += w4.x * v.x;
          acc[z4][1] += w4.y * v.y;
          acc[z4][2] += w4.z * v.z;
          acc[z4][3] += w4.w * v.w;
        }
      }
    }
  }
  // LN per token across the 32 lanes of this zg group, + GELU + store
  float4 g4 = *(const float4*)(gam + blk * 128 + c0);
  float4 e4 = *(const float4*)(bet + blk * 128 + c0);
  #pragma unroll
  for (int z4 = 0; z4 < 4; ++z4) {
    float s  = acc[z4][0] + acc[z4][1] + acc[z4][2] + acc[z4][3];
    float qq = acc[z4][0] * acc[z4][0] + acc[z4][1] * acc[z4][1]
             + acc[z4][2] * acc[z4][2] + acc[z4][3] * acc[z4][3];
    #pragma unroll
    for (int off = 16; off; off >>= 1) {
      s  += __shfl_down(s, off, 32);
      qq += __shfl_down(qq, off, 32);
    }
    s = __shfl(s, 0, 32); qq = __shfl(qq, 0, 32);
    float mean = s * (1.f / 128.f);
    float var = fmaxf(qq * (1.f / 128.f) - mean * mean, 0.f);
    float rstd = rsqrtf(var + 1e-6f);
    int z = zg * 4 + z4;
    float4 r;
    r.x = gelu((acc[z4][0] - mean) * rstd * g4.x + e4.x);
    r.y = gelu((acc[z4][1] - mean) * rstd * g4.y + e4.y);
    r.z = gelu((acc[z4][2] - mean) * rstd * g4.z + e4.z);
    r.w = gelu((acc[z4][3] - mean) * rstd * g4.w + e4.w);
    *(float4*)(out + (((size_t)b << 12) | (z << 8) | (yg << 4) | xg) * 128 + c0) = r;
  }
}

// attn[b,c,ki*128+k] += sum_l q[b,l,c]*K[b,l,k]
__global__ __launch_bounds__(256) void k_qk(
    const float* __restrict__ qtok, const float* __restrict__ ktok,
    float* __restrict__ attn, int ki) {
  __shared__ __align__(16) float qs[32][128];
  __shared__ __align__(16) float ks[32][128];
  int ls = blockIdx.x, b = blockIdx.y;
  const float* qb = qtok + (size_t)b * ((size_t)L * C);
  const float* kb = ktok + (size_t)b * ((size_t)L * C);
  int t = threadIdx.x;
  int tc = t & 15, tk = t >> 4;
  float acc[8][8];
  #pragma unroll
  for (int i = 0; i < 8; ++i)
    #pragma unroll
    for (int j = 0; j < 8; ++j) acc[i][j] = 0.f;
  for (int l0 = ls * 256; l0 < ls * 256 + 256; l0 += 32) {
    #pragma unroll
    for (int p = 0; p < 4; ++p) {
      int idx = p * 256 + t;
      int r = idx >> 5, c4 = (idx & 31) * 4;
      *(float4*)&qs[r][c4] = *(const float4*)&qb[(size_t)(l0 + r) * 128 + c4];
      *(float4*)&ks[r][c4] = *(const float4*)&kb[(size_t)(l0 + r) * 128 + c4];
    }
    __syncthreads();
    #pragma unroll 8
    for (int l = 0; l < 32; ++l) {
      float4 q0 = *(const float4*)&qs[l][tc * 8];
      float4 q1 = *(const float4*)&qs[l][tc * 8 + 4];
      float4 k0 = *(const float4*)&ks[l][tk * 8];
      float4 k1 = *(const float4*)&ks[l][tk * 8 + 4];
      float a[8]  = {q0.x, q0.y, q0.z, q0.w, q1.x, q1.y, q1.z, q1.w};
      float bb[8] = {k0.x, k0.y, k0.z, k0.w, k1.x, k1.y, k1.z, k1.w};
      #pragma unroll
      for (int i = 0; i < 8; ++i)
        #pragma unroll
        for (int j = 0; j < 8; ++j) acc[i][j] += a[i] * bb[j];
    }
    __syncthreads();
  }
  #pragma unroll
  for (int i = 0; i < 8; ++i) {
    int cc = tc * 8 + i;
    #pragma unroll
    for (int j = 0; j < 8; ++j) {
      int kk = ki * 128 + tk * 8 + j;
      atomicAdd(&attn[((size_t)b * 128 + cc) * 512 + kk], acc[i][j]);
    }
  }
}

// masked softmax over k=512 per (b,c) row; scale = 1/64.
__global__ __launch_bounds__(128) void k_sm(float* __restrict__ attn, const int* __restrict__ mask) {
  __shared__ float rm[2], rs[2];
  int b = blockIdx.x >> 7;
  float* row = attn + (size_t)blockIdx.x * 512;
  int t = threadIdx.x;
  float v[4];
  #pragma unroll
  for (int j = 0; j < 4; ++j) {
    int k = t + j * 128;
    v[j] = (mask[b * 4 + j] > 0) ? row[k] * 0.015625f : -1e30f;
  }
  float m = fmaxf(fmaxf(v[0], v[1]), fmaxf(v[2], v[3]));
  #pragma unroll
  for (int off = 32; off; off >>= 1) m = fmaxf(m, __shfl_down(m, off));
  if ((t & 63) == 0) rm[t >> 6] = m;
  __syncthreads();
  m = fmaxf(rm[0], rm[1]);
  float e[4], s = 0.f;
  #pragma unroll
  for (int j = 0; j < 4; ++j) { e[j] = expf(v[j] - m); s += e[j]; }
  #pragma unroll
  for (int off = 32; off; off >>= 1) s += __shfl_down(s, off);
  if ((t & 63) == 0) rs[t >> 6] = s;
  __syncthreads();
  float inv = 1.f / (rs[0] + rs[1]);
  #pragma unroll
  for (int j = 0; j < 4; ++j) row[t + j * 128] = e[j] * inv;
}

// x[b,l,c] += sum_{k in ki-block} P[b,c,ki*128+k] * V[b,l,k]
__global__ __launch_bounds__(128) void k_av(
    const float* __restrict__ attn, const float* __restrict__ vtok,
    float* __restrict__ xout, int ki) {
  __shared__ __align__(16) float vs[32][128];
  int l0 = blockIdx.x * 32, b = blockIdx.y;
  int t = threadIdx.x;
  const float* vb = vtok + ((size_t)b * L + l0) * 128;
  #pragma unroll
  for (int p = 0; p < 8; ++p) {
    int idx = p * 128 + t;
    int r = idx >> 5, c4 = (idx & 31) * 4;
    *(float4*)&vs[r][c4] = *(const float4*)&vb[(size_t)r * 128 + c4];
  }
  __syncthreads();
  const float* prow = attn + ((size_t)b * 128 + t) * 512 + ki * 128;
  float acc[32];
  #pragma unroll
  for (int i = 0; i < 32; ++i) acc[i] = 0.f;
  for (int k0 = 0; k0 < 128; k0 += 32) {
    float a[32];
    #pragma unroll
    for (int j = 0; j < 8; ++j) *(float4*)&a[j * 4] = *(const float4*)&prow[k0 + j * 4];
    #pragma unroll 8
    for (int tt = 0; tt < 32; ++tt) {
      #pragma unroll
      for (int j = 0; j < 32; ++j) acc[tt] += vs[tt][k0 + j] * a[j];
    }
  }
  #pragma unroll
  for (int tt = 0; tt < 32; ++tt)
    xout[(((size_t)b << 12) + l0 + tt) * 128 + t] += acc[tt];
}

// out[b,c,l] = query[b,c,l] + x9[b,l,c]
__global__ __launch_bounds__(256) void k_final(
    const void* __restrict__ qv, const float* __restrict__ xin, void* __restrict__ outv,
    const int* __restrict__ flagp) {
  __shared__ float tl[32][33];
  bool isb = (*flagp != 0);
  int l0 = blockIdx.x * 32, c0 = blockIdx.y * 32, b = blockIdx.z;
  int t = threadIdx.x;
  int cc = t & 31, lr = t >> 5;
  #pragma unroll
  for (int p = 0; p < 4; ++p) {
    int l = l0 + lr + p * 8;
    tl[lr + p * 8][cc] = xin[((((size_t)b) << 12) + l) * 128 + c0 + cc];
  }
  __syncthreads();
  int lw = t & 31, cr = t >> 5;
  #pragma unroll
  for (int p = 0; p < 4; ++p) {
    int c = c0 + cr + p * 8;
    size_t idx = (((size_t)b * 128 + c) << 12) + l0 + lw;
    float qf = isb ? b2f(((const bf16*)qv)[idx]) : ((const float*)qv)[idx];
    float r = qf + tl[lw][cr + p * 8];
    if (isb) ((bf16*)outv)[idx] = f2b(r);
    else     ((float*)outv)[idx] = r;
  }
}

extern "C" void kernel_launch(void* const* d_in, const int* in_sizes, int n_in,
                              void* d_out, int out_size, void* d_ws, size_t ws_size,
                              hipStream_t stream) {
  const void* vols[5] = {d_in[0], d_in[1], d_in[2], d_in[3], d_in[4]};
  const int* mask = (const int*)d_in[5];

  char* ws = (char*)d_ws;
  int*   flag  = (int*)(ws + OFF_FLAG);
  float* wts   = (float*)(ws + OFF_WTS);
  float* bufA  = (float*)(ws + OFF_A);
  float* bufB  = (float*)(ws + OFF_BB);
  float* qtok  = (float*)(ws + OFF_Q);
  float* kv    = (float*)(ws + OFF_KV);
  float* xattn = (float*)(ws + OFF_X);
  float* attn  = (float*)(ws + OFF_ATT);

  k_sniff<<<1, 64, 0, stream>>>((const unsigned*)d_in[0], flag);

  const size_t woff[12] = {W_PW1, W_PW1B, W_LN1G, W_LN1B, W_DWW, W_DWB,
                           W_LN2G, W_LN2B, W_PW2, W_PW2B, W_LN3G, W_LN3B};
  for (int i = 0; i < 12; ++i) {
    int n = in_sizes[6 + i];
    k_cvt<<<(n + 255) / 256, 256, 0, stream>>>(d_in[6 + i], wts + woff[i], n, flag);
  }
  const float *pw1_w = wts + W_PW1, *pw1_b = wts + W_PW1B, *ln1_g = wts + W_LN1G, *ln1_b = wts + W_LN1B;
  const float *dw_w = wts + W_DWW, *dw_b = wts + W_DWB, *ln2_g = wts + W_LN2G, *ln2_b = wts + W_LN2B;
  const float *pw2_w = wts + W_PW2, *pw2_b = wts + W_PW2B, *ln3_g = wts + W_LN3G, *ln3_b = wts + W_LN3B;

  dim3 tg(L / 32, 4, 8);
  auto run_block = [&](const void* src_vol, int blk, float* dst) {
    k_transpose<<<tg, 256, 0, stream>>>(src_vol, bufA, flag);
    k_pw_gemm<true><<<256, 256, 0, stream>>>(bufA, bufB, pw1_w, pw1_b, ln1_g, ln1_b, blk);
    k_dw_ln<<<2048, 128, 0, stream>>>(bufB, bufA, dw_w, dw_b, ln2_g, ln2_b, blk);
    k_pw_gemm<false><<<256, 256, 0, stream>>>(bufA, dst, pw2_w, pw2_b, ln3_g, ln3_b, blk);
  };

  run_block(vols[0], 0, qtok);

  hipMemsetAsync(attn, 0, (size_t)B * 128 * 512 * 4, stream);
  hipMemsetAsync(xattn, 0, VOLE * 4, stream);

  for (int m = 1; m <= 4; ++m) {
    run_block(vols[m], m, kv);
    k_qk<<<dim3(16, 8), 256, 0, stream>>>(qtok, kv, attn, m - 1);
  }

  k_sm<<<(int)(B * 128), 128, 0, stream>>>(attn, mask);

  for (int m = 1; m <= 4; ++m) {
    run_block(vols[m], 4 + m, kv);
    k_av<<<dim3(L / 32, B), 128, 0, stream>>>(attn, kv, xattn, m - 1);
  }

  k_pw_gemm<true><<<256, 256, 0, stream>>>(xattn, bufB, pw1_w, pw1_b, ln1_g, ln1_b, 9);
  k_dw_ln<<<2048, 128, 0, stream>>>(bufB, bufA, dw_w, dw_b, ln2_g, ln2_b, 9);
  k_pw_gemm<false><<<256, 256, 0, stream>>>(bufA, kv, pw2_w, pw2_b, ln3_g, ln3_b, 9);
  k_final<<<dim3(L / 32, 4, 8), 256, 0, stream>>>(vols[0], kv, d_out, flag);
}

// Round 7
// 2248.856 us; speedup vs baseline: 2.7883x; 1.1744x over previous
//
#include <hip/hip_runtime.h>
#include <hip/hip_bf16.h>

typedef __hip_bfloat16 bf16;
#define DEV __device__ __forceinline__

DEV float b2f(bf16 x) { return __bfloat162float(x); }
DEV bf16  f2b(float x) { return __float2bfloat16(x); }

typedef __attribute__((ext_vector_type(8))) short short8;   // 8 bf16 (4 VGPRs)
typedef __attribute__((ext_vector_type(4))) float f32x4;

static constexpr int B = 8, C = 128, S = 16;
static constexpr int L = S * S * S;                 // 4096
static constexpr size_t BL   = (size_t)B * L;       // 32768 tokens
static constexpr size_t VOLE = BL * C;              // 4,194,304 elements / volume

// ---- canonical f32 weight region (element offsets) ----
static constexpr size_t W_PW1  = 0;
static constexpr size_t W_PW1B = 163840;
static constexpr size_t W_LN1G = 165120;
static constexpr size_t W_LN1B = 166400;
static constexpr size_t W_DWW  = 167680;
static constexpr size_t W_DWB  = 202240;
static constexpr size_t W_LN2G = 203520;
static constexpr size_t W_LN2B = 204800;
static constexpr size_t W_PW2  = 206080;
static constexpr size_t W_PW2B = 369920;
static constexpr size_t W_LN3G = 371200;
static constexpr size_t W_LN3B = 372480;

// ---- workspace layout (bytes). ~86 MB. ----
static constexpr size_t OFF_FLAG = 0;
static constexpr size_t OFF_WTS  = 256;                     // f32 canonical weights (1.5 MB)
static constexpr size_t OFF_WHI1 = 1572864;                 // bf16 pw1_w hi [10][128][128]
static constexpr size_t OFF_WLO1 = OFF_WHI1 + 327680;       // bf16 pw1_w lo
static constexpr size_t OFF_WHI2 = OFF_WLO1 + 327680;       // bf16 pw2_w hi
static constexpr size_t OFF_WLO2 = OFF_WHI2 + 327680;       // bf16 pw2_w lo
static constexpr size_t OFF_A    = 4u << 20;
static constexpr size_t OFF_BB   = OFF_A  + VOLE * 4;
static constexpr size_t OFF_Q    = OFF_BB + VOLE * 4;
static constexpr size_t OFF_KV   = OFF_Q  + VOLE * 4;
static constexpr size_t OFF_X    = OFF_KV + VOLE * 4;
static constexpr size_t OFF_ATT  = OFF_X  + VOLE * 4;

DEV float gelu(float x) { return 0.5f * x * (1.f + erff(x * 0.70710678118654752f)); }

// ---- dtype sniffer: flag=1 if inputs are bf16, 0 if f32. ----
__global__ void k_sniff(const unsigned* __restrict__ q, int* __restrict__ flag) {
  int t = threadIdx.x;
  unsigned u = q[t];
  int good = 0;
  #pragma unroll
  for (int h = 0; h < 2; ++h) {
    unsigned hb = (h ? (u & 0xffff0000u) : (u << 16));
    float v = __uint_as_float(hb);
    float a = fabsf(v);
    if (v == 0.f || (a > 1e-20f && a < 100.f)) good++;
  }
  #pragma unroll
  for (int off = 32; off; off >>= 1) good += __shfl_down(good, off);
  if (t == 0) *flag = (good >= 112) ? 1 : 0;
}

__global__ void k_cvt(const void* __restrict__ src, float* __restrict__ dst, int n,
                      const int* __restrict__ flagp) {
  int i = blockIdx.x * 256 + threadIdx.x;
  if (i >= n) return;
  if (*flagp) dst[i] = b2f(((const bf16*)src)[i]);
  else        dst[i] = ((const float*)src)[i];
}

// weights for MFMA pw: f32 canonical + bf16 hi/lo split
__global__ void k_cvtw(const void* __restrict__ src, float* __restrict__ dst,
                       bf16* __restrict__ dhi, bf16* __restrict__ dlo, int n,
                       const int* __restrict__ flagp) {
  int i = blockIdx.x * 256 + threadIdx.x;
  if (i >= n) return;
  float v = (*flagp) ? b2f(((const bf16*)src)[i]) : ((const float*)src)[i];
  dst[i] = v;
  bf16 h = f2b(v);
  dhi[i] = h;
  dlo[i] = f2b(v - b2f(h));
}

// [B,C,L] -> [B,L,C] for ONE volume, LDS-tiled, dtype-branched loads, f32 out.
__global__ __launch_bounds__(256) void k_transpose(const void* __restrict__ sv,
                                                   float* __restrict__ d,
                                                   const int* __restrict__ flagp) {
  __shared__ float t[32][33];
  bool isb = (*flagp != 0);
  int b = blockIdx.z;
  int c0 = blockIdx.y * 32, l0 = blockIdx.x * 32;
  int tid = threadIdx.x;
  int lr = tid & 31, cr = tid >> 5;
  #pragma unroll
  for (int i = 0; i < 4; ++i) {
    size_t si = ((size_t)b * C + (c0 + cr + i * 8)) * L + l0 + lr;
    t[cr + i * 8][lr] = isb ? b2f(((const bf16*)sv)[si]) : ((const float*)sv)[si];
  }
  __syncthreads();
  int cw = tid & 31, lw = tid >> 5;
  #pragma unroll
  for (int i = 0; i < 4; ++i) {
    int l = l0 + lw + i * 8;
    d[((size_t)b * L + l) * C + c0 + cw] = t[cw][lw + i * 8];
  }
}

// ---- pointwise conv via split-precision MFMA (hi/lo bf16, 3 terms) + bias+LN(+GELU). ----
// Block: 256 thr (4 waves), tile 128 tokens x 128 outputs, K=128.
// out[m][o] = sum_k x[m][k] * W[o][k];  x ~ xhi+xlo, W ~ Whi+Wlo (lo*lo dropped).
template <bool DOGELU>
__global__ __launch_bounds__(256) void k_pw_mfma(
    const float* __restrict__ in, float* __restrict__ out,
    const bf16* __restrict__ Whi, const bf16* __restrict__ Wlo,
    const float* __restrict__ bias,
    const float* __restrict__ gam, const float* __restrict__ bet, int blk) {
  __shared__ __align__(16) char smem[128 * 136 * 2 * 2];   // 69,632 B
  bf16* xh = (bf16*)smem;                                  // [128 m][136] hi
  bf16* xl = (bf16*)(smem + 128 * 136 * 2);                // [128 m][136] lo
  float* ys = (float*)smem;                                // epilogue: [128 m][132]
  int t = threadIdx.x;
  size_t tok0 = (size_t)blockIdx.x * 128;
  const bf16* Wh = Whi + ((size_t)blk << 14);
  const bf16* Wl = Wlo + ((size_t)blk << 14);
  // stage x hi/lo (f32 -> bf16 split), coalesced global read, 8B LDS writes
  #pragma unroll
  for (int p = 0; p < 16; ++p) {
    int idx = p * 256 + t;
    int m = idx >> 5, c4 = (idx & 31) * 4;
    float4 v = *(const float4*)(in + (tok0 + m) * 128 + c4);
    bf16 hi[4] = {f2b(v.x), f2b(v.y), f2b(v.z), f2b(v.w)};
    bf16 lo[4] = {f2b(v.x - b2f(hi[0])), f2b(v.y - b2f(hi[1])),
                  f2b(v.z - b2f(hi[2])), f2b(v.w - b2f(hi[3]))};
    *(ushort4*)(xh + m * 136 + c4) = *(ushort4*)hi;
    *(ushort4*)(xl + m * 136 + c4) = *(ushort4*)lo;
  }
  __syncthreads();
  int w = t >> 6, lane = t & 63;
  int wm = (w >> 1) * 64, wo = (w & 1) * 64;   // wave's 64x64 sub-tile origin
  int cl = lane & 15, q = lane >> 4;
  f32x4 acc[4][4] = {};                         // [m-tile][o-tile]
  #pragma unroll
  for (int ks = 0; ks < 4; ++ks) {
    int k = ks * 32 + q * 8;
    short8 ah[4], al[4], bh[4], blo[4];
    #pragma unroll
    for (int i = 0; i < 4; ++i) {
      ah[i] = *(const short8*)(xh + (wm + i * 16 + cl) * 136 + k);
      al[i] = *(const short8*)(xl + (wm + i * 16 + cl) * 136 + k);
    }
    #pragma unroll
    for (int j = 0; j < 4; ++j) {
      size_t wi = (size_t)(wo + j * 16 + cl) * 128 + k;
      bh[j]  = *(const short8*)(Wh + wi);
      blo[j] = *(const short8*)(Wl + wi);
    }
    #pragma unroll
    for (int i = 0; i < 4; ++i)
      #pragma unroll
      for (int j = 0; j < 4; ++j) {
        acc[i][j] = __builtin_amdgcn_mfma_f32_16x16x32_bf16(ah[i], bh[j],  acc[i][j], 0, 0, 0);
        acc[i][j] = __builtin_amdgcn_mfma_f32_16x16x32_bf16(ah[i], blo[j], acc[i][j], 0, 0, 0);
        acc[i][j] = __builtin_amdgcn_mfma_f32_16x16x32_bf16(al[i], bh[j],  acc[i][j], 0, 0, 0);
      }
  }
  // bias per (j, cl): o = wo + j*16 + cl
  float blv[4];
  #pragma unroll
  for (int j = 0; j < 4; ++j) blv[j] = bias[blk * 128 + wo + j * 16 + cl];
  __syncthreads();
  // park D+bias: D[row=q*4+r][col=cl] per 16x16 tile
  #pragma unroll
  for (int i = 0; i < 4; ++i)
    #pragma unroll
    for (int j = 0; j < 4; ++j)
      #pragma unroll
      for (int r = 0; r < 4; ++r)
        ys[(wm + i * 16 + q * 4 + r) * 132 + wo + j * 16 + cl] = acc[i][j][r] + blv[j];
  __syncthreads();
  // LN: thread -> (token m = t>>1, half = t&1 covering 64 channels)
  int m = t >> 1, half = t & 1;
  const float* yr = ys + (size_t)m * 132 + half * 64;
  float s = 0.f, q2 = 0.f;
  #pragma unroll
  for (int jj = 0; jj < 16; ++jj) {
    float4 v = *(const float4*)(yr + jj * 4);
    s  += v.x + v.y + v.z + v.w;
    q2 += v.x * v.x + v.y * v.y + v.z * v.z + v.w * v.w;
  }
  s  += __shfl_xor(s, 1);
  q2 += __shfl_xor(q2, 1);
  float mean = s * (1.f / 128.f);
  float var = fmaxf(q2 * (1.f / 128.f) - mean * mean, 0.f);
  float rstd = rsqrtf(var + 1e-6f);
  #pragma unroll
  for (int jj = 0; jj < 16; ++jj) {
    int c = half * 64 + jj * 4;
    float4 v = *(const float4*)(yr + jj * 4);
    float4 g = *(const float4*)(gam + blk * 128 + c);
    float4 e = *(const float4*)(bet + blk * 128 + c);
    float4 r;
    r.x = (v.x - mean) * rstd * g.x + e.x;
    r.y = (v.y - mean) * rstd * g.y + e.y;
    r.z = (v.z - mean) * rstd * g.z + e.z;
    r.w = (v.w - mean) * rstd * g.w + e.w;
    if (DOGELU) { r.x = gelu(r.x); r.y = gelu(r.y); r.z = gelu(r.z); r.w = gelu(r.w); }
    *(float4*)(out + (tok0 + m) * 128 + c) = r;
  }
}

// ---- depthwise 3x3x3 + bias + LN + GELU. ----
__global__ __launch_bounds__(128) void k_dw_ln(
    const float* __restrict__ in, float* __restrict__ out,
    const float* __restrict__ W, const float* __restrict__ bias,
    const float* __restrict__ gam, const float* __restrict__ bet, int blk) {
  __shared__ __align__(16) float ls[9][16][128];
  __shared__ __align__(16) float dww[27][128];
  int t = threadIdx.x;
  int xg = blockIdx.x & 15, yg = (blockIdx.x >> 4) & 15, b = blockIdx.x >> 8;
  const float* base = in + (((size_t)b) << 12) * 128;
  const float* Wb = W + (size_t)blk * 3456;
  #pragma unroll
  for (int i = 0; i < 27; ++i) dww[i][t] = Wb[t * 27 + i];
  {
    int c4 = (t & 31) * 4, z0 = (t >> 5) * 4;
    for (int col = 0; col < 9; ++col) {
      int yy = yg + col / 3 - 1, xx = xg + col % 3 - 1;
      bool ok = ((unsigned)yy < 16u) && ((unsigned)xx < 16u);
      #pragma unroll
      for (int w = 0; w < 4; ++w) {
        int z = z0 + w;
        float4 v = {0.f, 0.f, 0.f, 0.f};
        if (ok) v = *(const float4*)(base + ((size_t)((z << 8) | (yy << 4) | xx)) * 128 + c4);
        *(float4*)&ls[col][z][c4] = v;
      }
    }
  }
  __syncthreads();
  int q = t & 31, zg = t >> 5;
  int c0 = q * 4;
  float4 bias4 = *(const float4*)(bias + blk * 128 + c0);
  float acc[4][4];
  #pragma unroll
  for (int z4 = 0; z4 < 4; ++z4) {
    acc[z4][0] = bias4.x; acc[z4][1] = bias4.y; acc[z4][2] = bias4.z; acc[z4][3] = bias4.w;
  }
  #pragma unroll
  for (int ky = 0; ky < 3; ++ky) {
    #pragma unroll
    for (int kx = 0; kx < 3; ++kx) {
      int col = ky * 3 + kx;
      float4 cv[6];
      #pragma unroll
      for (int zz = 0; zz < 6; ++zz) {
        int z = zg * 4 + zz - 1;
        if ((unsigned)z < 16u) cv[zz] = *(const float4*)&ls[col][z][c0];
        else                   cv[zz] = {0.f, 0.f, 0.f, 0.f};
      }
      #pragma unroll
      for (int kz = 0; kz < 3; ++kz) {
        float4 w4 = *(const float4*)&dww[kz * 9 + col][c0];
        #pragma unroll
        for (int z4 = 0; z4 < 4; ++z4) {
          float4 v = cv[z4 + kz];
          acc[z4][0] += w4.x * v.x;
          acc[z4][1] += w4.y * v.y;
          acc[z4][2] += w4.z * v.z;
          acc[z4][3] += w4.w * v.w;
        }
      }
    }
  }
  float4 g4 = *(const float4*)(gam + blk * 128 + c0);
  float4 e4 = *(const float4*)(bet + blk * 128 + c0);
  #pragma unroll
  for (int z4 = 0; z4 < 4; ++z4) {
    float s  = acc[z4][0] + acc[z4][1] + acc[z4][2] + acc[z4][3];
    float qq = acc[z4][0] * acc[z4][0] + acc[z4][1] * acc[z4][1]
             + acc[z4][2] * acc[z4][2] + acc[z4][3] * acc[z4][3];
    #pragma unroll
    for (int off = 16; off; off >>= 1) {
      s  += __shfl_down(s, off, 32);
      qq += __shfl_down(qq, off, 32);
    }
    s = __shfl(s, 0, 32); qq = __shfl(qq, 0, 32);
    float mean = s * (1.f / 128.f);
    float var = fmaxf(qq * (1.f / 128.f) - mean * mean, 0.f);
    float rstd = rsqrtf(var + 1e-6f);
    int z = zg * 4 + z4;
    float4 r;
    r.x = gelu((acc[z4][0] - mean) * rstd * g4.x + e4.x);
    r.y = gelu((acc[z4][1] - mean) * rstd * g4.y + e4.y);
    r.z = gelu((acc[z4][2] - mean) * rstd * g4.z + e4.z);
    r.w = gelu((acc[z4][3] - mean) * rstd * g4.w + e4.w);
    *(float4*)(out + (((size_t)b << 12) | (z << 8) | (yg << 4) | xg) * 128 + c0) = r;
  }
}

// attn[b,c,ki*128+k] += sum_l q[b,l,c]*K[b,l,k]. 64 l-splits, 4+4 blocking.
__global__ __launch_bounds__(256) void k_qk(
    const float* __restrict__ qtok, const float* __restrict__ ktok,
    float* __restrict__ attn, int ki) {
  __shared__ __align__(16) float qs[32][128];
  __shared__ __align__(16) float ks[32][128];
  int ls = blockIdx.x, b = blockIdx.y;
  const float* qb = qtok + (size_t)b * ((size_t)L * C);
  const float* kb = ktok + (size_t)b * ((size_t)L * C);
  int t = threadIdx.x;
  int tc = t & 15, tk = t >> 4;
  float acc[8][8];
  #pragma unroll
  for (int i = 0; i < 8; ++i)
    #pragma unroll
    for (int j = 0; j < 8; ++j) acc[i][j] = 0.f;
  for (int l0 = ls * 64; l0 < ls * 64 + 64; l0 += 32) {
    #pragma unroll
    for (int p = 0; p < 4; ++p) {
      int idx = p * 256 + t;
      int r = idx >> 5, c4 = (idx & 31) * 4;
      *(float4*)&qs[r][c4] = *(const float4*)&qb[(size_t)(l0 + r) * 128 + c4];
      *(float4*)&ks[r][c4] = *(const float4*)&kb[(size_t)(l0 + r) * 128 + c4];
    }
    __syncthreads();
    #pragma unroll 4
    for (int l = 0; l < 32; ++l) {
      float4 q0 = *(const float4*)&qs[l][tc * 4];
      float4 q1 = *(const float4*)&qs[l][tc * 4 + 64];
      float4 k0 = *(const float4*)&ks[l][tk * 4];
      float4 k1 = *(const float4*)&ks[l][tk * 4 + 64];
      float a[8]  = {q0.x, q0.y, q0.z, q0.w, q1.x, q1.y, q1.z, q1.w};
      float bb[8] = {k0.x, k0.y, k0.z, k0.w, k1.x, k1.y, k1.z, k1.w};
      #pragma unroll
      for (int i = 0; i < 8; ++i)
        #pragma unroll
        for (int j = 0; j < 8; ++j) acc[i][j] += a[i] * bb[j];
    }
    __syncthreads();
  }
  #pragma unroll
  for (int ih = 0; ih < 2; ++ih)
    #pragma unroll
    for (int i = 0; i < 4; ++i) {
      int c = tc * 4 + ih * 64 + i;
      #pragma unroll
      for (int jh = 0; jh < 2; ++jh)
        #pragma unroll
        for (int j = 0; j < 4; ++j) {
          int kk = ki * 128 + tk * 4 + jh * 64 + j;
          atomicAdd(&attn[((size_t)b * 128 + c) * 512 + kk], acc[ih * 4 + i][jh * 4 + j]);
        }
    }
}

// masked softmax over k=512 per (b,c) row; scale = 1/64.
__global__ __launch_bounds__(128) void k_sm(float* __restrict__ attn, const int* __restrict__ mask) {
  __shared__ float rm[2], rs[2];
  int b = blockIdx.x >> 7;
  float* row = attn + (size_t)blockIdx.x * 512;
  int t = threadIdx.x;
  float v[4];
  #pragma unroll
  for (int j = 0; j < 4; ++j) {
    int k = t + j * 128;
    v[j] = (mask[b * 4 + j] > 0) ? row[k] * 0.015625f : -1e30f;
  }
  float m = fmaxf(fmaxf(v[0], v[1]), fmaxf(v[2], v[3]));
  #pragma unroll
  for (int off = 32; off; off >>= 1) m = fmaxf(m, __shfl_down(m, off));
  if ((t & 63) == 0) rm[t >> 6] = m;
  __syncthreads();
  m = fmaxf(rm[0], rm[1]);
  float e[4], s = 0.f;
  #pragma unroll
  for (int j = 0; j < 4; ++j) { e[j] = expf(v[j] - m); s += e[j]; }
  #pragma unroll
  for (int off = 32; off; off >>= 1) s += __shfl_down(s, off);
  if ((t & 63) == 0) rs[t >> 6] = s;
  __syncthreads();
  float inv = 1.f / (rs[0] + rs[1]);
  #pragma unroll
  for (int j = 0; j < 4; ++j) row[t + j * 128] = e[j] * inv;
}

// x[b,l,c] += sum_{k in ki-block} P[b,c,k] * V[b,l,k]. Tile 64l x 128c, k-chunks of 64.
__global__ __launch_bounds__(256) void k_av(
    const float* __restrict__ attn, const float* __restrict__ vtok,
    float* __restrict__ xout, int ki) {
  __shared__ float ps[128][65];
  __shared__ float vs[64][65];
  int l0 = blockIdx.x * 64, b = blockIdx.y;
  int t = threadIdx.x;
  int tx = t & 15, ty = t >> 4;
  float acc[4][8];
  #pragma unroll
  for (int i = 0; i < 4; ++i)
    #pragma unroll
    for (int j = 0; j < 8; ++j) acc[i][j] = 0.f;
  for (int kc = 0; kc < 2; ++kc) {
    #pragma unroll
    for (int p = 0; p < 8; ++p) {
      int idx = p * 256 + t;
      int c = idx >> 4, kq = (idx & 15) * 4;
      float4 v = *(const float4*)&attn[((size_t)b * 128 + c) * 512 + ki * 128 + kc * 64 + kq];
      ps[c][kq] = v.x; ps[c][kq + 1] = v.y; ps[c][kq + 2] = v.z; ps[c][kq + 3] = v.w;
    }
    #pragma unroll
    for (int p = 0; p < 4; ++p) {
      int idx = p * 256 + t;
      int l = idx >> 4, kq = (idx & 15) * 4;
      float4 v = *(const float4*)&vtok[((size_t)b * L + l0 + l) * 128 + kc * 64 + kq];
      vs[l][kq] = v.x; vs[l][kq + 1] = v.y; vs[l][kq + 2] = v.z; vs[l][kq + 3] = v.w;
    }
    __syncthreads();
    #pragma unroll 4
    for (int k = 0; k < 64; ++k) {
      float pv[8], vv[4];
      #pragma unroll
      for (int j = 0; j < 4; ++j) {
        pv[j]     = ps[tx * 4 + j][k];
        pv[j + 4] = ps[tx * 4 + 64 + j][k];
      }
      #pragma unroll
      for (int i = 0; i < 4; ++i) vv[i] = vs[ty * 4 + i][k];
      #pragma unroll
      for (int i = 0; i < 4; ++i)
        #pragma unroll
        for (int j = 0; j < 8; ++j) acc[i][j] += vv[i] * pv[j];
    }
    __syncthreads();
  }
  #pragma unroll
  for (int i = 0; i < 4; ++i) {
    float* xr = xout + ((size_t)b * L + l0 + ty * 4 + i) * 128;
    float4* p0 = (float4*)(xr + tx * 4);
    float4* p1 = (float4*)(xr + tx * 4 + 64);
    float4 o0 = *p0, o1 = *p1;
    o0.x += acc[i][0]; o0.y += acc[i][1]; o0.z += acc[i][2]; o0.w += acc[i][3];
    o1.x += acc[i][4]; o1.y += acc[i][5]; o1.z += acc[i][6]; o1.w += acc[i][7];
    *p0 = o0; *p1 = o1;
  }
}

// out[b,c,l] = query[b,c,l] + x9[b,l,c]
__global__ __launch_bounds__(256) void k_final(
    const void* __restrict__ qv, const float* __restrict__ xin, void* __restrict__ outv,
    const int* __restrict__ flagp) {
  __shared__ float tl[32][33];
  bool isb = (*flagp != 0);
  int l0 = blockIdx.x * 32, c0 = blockIdx.y * 32, b = blockIdx.z;
  int t = threadIdx.x;
  int cc = t & 31, lr = t >> 5;
  #pragma unroll
  for (int p = 0; p < 4; ++p) {
    int l = l0 + lr + p * 8;
    tl[lr + p * 8][cc] = xin[((((size_t)b) << 12) + l) * 128 + c0 + cc];
  }
  __syncthreads();
  int lw = t & 31, cr = t >> 5;
  #pragma unroll
  for (int p = 0; p < 4; ++p) {
    int c = c0 + cr + p * 8;
    size_t idx = (((size_t)b * 128 + c) << 12) + l0 + lw;
    float qf = isb ? b2f(((const bf16*)qv)[idx]) : ((const float*)qv)[idx];
    float r = qf + tl[lw][cr + p * 8];
    if (isb) ((bf16*)outv)[idx] = f2b(r);
    else     ((float*)outv)[idx] = r;
  }
}

extern "C" void kernel_launch(void* const* d_in, const int* in_sizes, int n_in,
                              void* d_out, int out_size, void* d_ws, size_t ws_size,
                              hipStream_t stream) {
  const void* vols[5] = {d_in[0], d_in[1], d_in[2], d_in[3], d_in[4]};
  const int* mask = (const int*)d_in[5];

  char* ws = (char*)d_ws;
  int*   flag  = (int*)(ws + OFF_FLAG);
  float* wts   = (float*)(ws + OFF_WTS);
  bf16*  whi1  = (bf16*)(ws + OFF_WHI1);
  bf16*  wlo1  = (bf16*)(ws + OFF_WLO1);
  bf16*  whi2  = (bf16*)(ws + OFF_WHI2);
  bf16*  wlo2  = (bf16*)(ws + OFF_WLO2);
  float* bufA  = (float*)(ws + OFF_A);
  float* bufB  = (float*)(ws + OFF_BB);
  float* qtok  = (float*)(ws + OFF_Q);
  float* kv    = (float*)(ws + OFF_KV);
  float* xattn = (float*)(ws + OFF_X);
  float* attn  = (float*)(ws + OFF_ATT);

  k_sniff<<<1, 64, 0, stream>>>((const unsigned*)d_in[0], flag);

  const size_t woff[12] = {W_PW1, W_PW1B, W_LN1G, W_LN1B, W_DWW, W_DWB,
                           W_LN2G, W_LN2B, W_PW2, W_PW2B, W_LN3G, W_LN3B};
  for (int i = 0; i < 12; ++i) {
    int n = in_sizes[6 + i];
    if (i == 0)
      k_cvtw<<<(n + 255) / 256, 256, 0, stream>>>(d_in[6 + i], wts + woff[i], whi1, wlo1, n, flag);
    else if (i == 8)
      k_cvtw<<<(n + 255) / 256, 256, 0, stream>>>(d_in[6 + i], wts + woff[i], whi2, wlo2, n, flag);
    else
      k_cvt<<<(n + 255) / 256, 256, 0, stream>>>(d_in[6 + i], wts + woff[i], n, flag);
  }
  const float *pw1_b = wts + W_PW1B, *ln1_g = wts + W_LN1G, *ln1_b = wts + W_LN1B;
  const float *dw_w = wts + W_DWW, *dw_b = wts + W_DWB, *ln2_g = wts + W_LN2G, *ln2_b = wts + W_LN2B;
  const float *pw2_b = wts + W_PW2B, *ln3_g = wts + W_LN3G, *ln3_b = wts + W_LN3B;

  dim3 tg(L / 32, 4, 8);
  auto run_block = [&](const void* src_vol, int blk, float* dst) {
    k_transpose<<<tg, 256, 0, stream>>>(src_vol, bufA, flag);
    k_pw_mfma<true><<<256, 256, 0, stream>>>(bufA, bufB, whi1, wlo1, pw1_b, ln1_g, ln1_b, blk);
    k_dw_ln<<<2048, 128, 0, stream>>>(bufB, bufA, dw_w, dw_b, ln2_g, ln2_b, blk);
    k_pw_mfma<false><<<256, 256, 0, stream>>>(bufA, dst, whi2, wlo2, pw2_b, ln3_g, ln3_b, blk);
  };

  run_block(vols[0], 0, qtok);

  hipMemsetAsync(attn, 0, (size_t)B * 128 * 512 * 4, stream);
  hipMemsetAsync(xattn, 0, VOLE * 4, stream);

  for (int m = 1; m <= 4; ++m) {
    run_block(vols[m], m, kv);
    k_qk<<<dim3(64, 8), 256, 0, stream>>>(qtok, kv, attn, m - 1);
  }

  k_sm<<<(int)(B * 128), 128, 0, stream>>>(attn, mask);

  for (int m = 1; m <= 4; ++m) {
    run_block(vols[m], 4 + m, kv);
    k_av<<<dim3(64, 8), 256, 0, stream>>>(attn, kv, xattn, m - 1);
  }

  k_pw_mfma<true><<<256, 256, 0, stream>>>(xattn, bufB, whi1, wlo1, pw1_b, ln1_g, ln1_b, 9);
  k_dw_ln<<<2048, 128, 0, stream>>>(bufB, bufA, dw_w, dw_b, ln2_g, ln2_b, 9);
  k_pw_mfma<false><<<256, 256, 0, stream>>>(bufA, kv, whi2, wlo2, pw2_b, ln3_g, ln3_b, 9);
  k_final<<<dim3(L / 32, 4, 8), 256, 0, stream>>>(vols[0], kv, d_out, flag);
}

// Round 8
// 1660.953 us; speedup vs baseline: 3.7752x; 1.3540x over previous
//
#include <hip/hip_runtime.h>
#include <hip/hip_bf16.h>

typedef __hip_bfloat16 bf16;
#define DEV __device__ __forceinline__

DEV float b2f(bf16 x) { return __bfloat162float(x); }
DEV bf16  f2b(float x) { return __float2bfloat16(x); }

typedef __attribute__((ext_vector_type(8))) short short8;   // 8 bf16 (4 VGPRs)
typedef __attribute__((ext_vector_type(4))) float f32x4;

static constexpr int B = 8, C = 128, S = 16;
static constexpr int L = S * S * S;                 // 4096
static constexpr size_t BL   = (size_t)B * L;       // 32768 tokens
static constexpr size_t VOLE = BL * C;              // 4,194,304 elements / volume

// ---- canonical f32 weight region (element offsets) ----
static constexpr size_t W_PW1  = 0;
static constexpr size_t W_PW1B = 163840;
static constexpr size_t W_LN1G = 165120;
static constexpr size_t W_LN1B = 166400;
static constexpr size_t W_DWW  = 167680;
static constexpr size_t W_DWB  = 202240;
static constexpr size_t W_LN2G = 203520;
static constexpr size_t W_LN2B = 204800;
static constexpr size_t W_PW2  = 206080;
static constexpr size_t W_PW2B = 369920;
static constexpr size_t W_LN3G = 371200;
static constexpr size_t W_LN3B = 372480;

// ---- workspace layout (bytes). ~86 MB. ----
static constexpr size_t OFF_FLAG = 0;
static constexpr size_t OFF_WTS  = 256;                     // f32 canonical weights (1.5 MB)
static constexpr size_t OFF_WHI1 = 1572864;                 // bf16 pw1_w hi [10][128][128]
static constexpr size_t OFF_WLO1 = OFF_WHI1 + 327680;       // bf16 pw1_w lo
static constexpr size_t OFF_WHI2 = OFF_WLO1 + 327680;       // bf16 pw2_w hi
static constexpr size_t OFF_WLO2 = OFF_WHI2 + 327680;       // bf16 pw2_w lo
static constexpr size_t OFF_A    = 4u << 20;
static constexpr size_t OFF_BB   = OFF_A  + VOLE * 4;
static constexpr size_t OFF_Q    = OFF_BB + VOLE * 4;
static constexpr size_t OFF_KV   = OFF_Q  + VOLE * 4;
static constexpr size_t OFF_X    = OFF_KV + VOLE * 4;
static constexpr size_t OFF_ATT  = OFF_X  + VOLE * 4;

DEV float gelu(float x) { return 0.5f * x * (1.f + erff(x * 0.70710678118654752f)); }

// ---- dtype sniffer: flag=1 if inputs are bf16, 0 if f32. ----
__global__ void k_sniff(const unsigned* __restrict__ q, int* __restrict__ flag) {
  int t = threadIdx.x;
  unsigned u = q[t];
  int good = 0;
  #pragma unroll
  for (int h = 0; h < 2; ++h) {
    unsigned hb = (h ? (u & 0xffff0000u) : (u << 16));
    float v = __uint_as_float(hb);
    float a = fabsf(v);
    if (v == 0.f || (a > 1e-20f && a < 100.f)) good++;
  }
  #pragma unroll
  for (int off = 32; off; off >>= 1) good += __shfl_down(good, off);
  if (t == 0) *flag = (good >= 112) ? 1 : 0;
}

__global__ void k_cvt(const void* __restrict__ src, float* __restrict__ dst, int n,
                      const int* __restrict__ flagp) {
  int i = blockIdx.x * 256 + threadIdx.x;
  if (i >= n) return;
  if (*flagp) dst[i] = b2f(((const bf16*)src)[i]);
  else        dst[i] = ((const float*)src)[i];
}

// weights for MFMA pw: f32 canonical + bf16 hi/lo split
__global__ void k_cvtw(const void* __restrict__ src, float* __restrict__ dst,
                       bf16* __restrict__ dhi, bf16* __restrict__ dlo, int n,
                       const int* __restrict__ flagp) {
  int i = blockIdx.x * 256 + threadIdx.x;
  if (i >= n) return;
  float v = (*flagp) ? b2f(((const bf16*)src)[i]) : ((const float*)src)[i];
  dst[i] = v;
  bf16 h = f2b(v);
  dhi[i] = h;
  dlo[i] = f2b(v - b2f(h));
}

// [B,C,L] -> [B,L,C] for ONE volume, LDS-tiled, dtype-branched loads, f32 out.
__global__ __launch_bounds__(256) void k_transpose(const void* __restrict__ sv,
                                                   float* __restrict__ d,
                                                   const int* __restrict__ flagp) {
  __shared__ float t[32][33];
  bool isb = (*flagp != 0);
  int b = blockIdx.z;
  int c0 = blockIdx.y * 32, l0 = blockIdx.x * 32;
  int tid = threadIdx.x;
  int lr = tid & 31, cr = tid >> 5;
  #pragma unroll
  for (int i = 0; i < 4; ++i) {
    size_t si = ((size_t)b * C + (c0 + cr + i * 8)) * L + l0 + lr;
    t[cr + i * 8][lr] = isb ? b2f(((const bf16*)sv)[si]) : ((const float*)sv)[si];
  }
  __syncthreads();
  int cw = tid & 31, lw = tid >> 5;
  #pragma unroll
  for (int i = 0; i < 4; ++i) {
    int l = l0 + lw + i * 8;
    d[((size_t)b * L + l) * C + c0 + cw] = t[cw][lw + i * 8];
  }
}

// ---- pointwise conv via split-precision MFMA (hi/lo bf16) + bias+LN(+GELU). ----
// XEXACT: input known bf16-exact when flag==1 -> x_lo == 0, skip third term.
template <bool DOGELU, bool XEXACT>
__global__ __launch_bounds__(256) void k_pw_mfma(
    const float* __restrict__ in, float* __restrict__ out,
    const bf16* __restrict__ Whi, const bf16* __restrict__ Wlo,
    const float* __restrict__ bias,
    const float* __restrict__ gam, const float* __restrict__ bet, int blk,
    const int* __restrict__ flagp) {
  __shared__ __align__(16) char smem[128 * 136 * 2 * 2];   // 69,632 B
  bf16* xh = (bf16*)smem;                                  // [128 m][136] hi
  bf16* xl = (bf16*)(smem + 128 * 136 * 2);                // [128 m][136] lo
  float* ys = (float*)smem;                                // epilogue: [128 m][132]
  int t = threadIdx.x;
  bool ex = XEXACT && (*flagp != 0);
  size_t tok0 = (size_t)blockIdx.x * 128;
  const bf16* Wh = Whi + ((size_t)blk << 14);
  const bf16* Wl = Wlo + ((size_t)blk << 14);
  // stage x hi/lo (f32 -> bf16 split), coalesced global read, 8B LDS writes
  #pragma unroll
  for (int p = 0; p < 16; ++p) {
    int idx = p * 256 + t;
    int m = idx >> 5, c4 = (idx & 31) * 4;
    float4 v = *(const float4*)(in + (tok0 + m) * 128 + c4);
    bf16 hi[4] = {f2b(v.x), f2b(v.y), f2b(v.z), f2b(v.w)};
    *(ushort4*)(xh + m * 136 + c4) = *(ushort4*)hi;
    if (!ex) {
      bf16 lo[4] = {f2b(v.x - b2f(hi[0])), f2b(v.y - b2f(hi[1])),
                    f2b(v.z - b2f(hi[2])), f2b(v.w - b2f(hi[3]))};
      *(ushort4*)(xl + m * 136 + c4) = *(ushort4*)lo;
    }
  }
  __syncthreads();
  int w = t >> 6, lane = t & 63;
  int wm = (w >> 1) * 64, wo = (w & 1) * 64;   // wave's 64x64 sub-tile origin
  int cl = lane & 15, q = lane >> 4;
  f32x4 acc[4][4] = {};                         // [m-tile][o-tile]
  #pragma unroll
  for (int ks = 0; ks < 4; ++ks) {
    int k = ks * 32 + q * 8;
    short8 ah[4], al[4], bh[4], blo[4];
    #pragma unroll
    for (int i = 0; i < 4; ++i) {
      ah[i] = *(const short8*)(xh + (wm + i * 16 + cl) * 136 + k);
      if (!ex) al[i] = *(const short8*)(xl + (wm + i * 16 + cl) * 136 + k);
    }
    #pragma unroll
    for (int j = 0; j < 4; ++j) {
      size_t wi = (size_t)(wo + j * 16 + cl) * 128 + k;
      bh[j]  = *(const short8*)(Wh + wi);
      blo[j] = *(const short8*)(Wl + wi);
    }
    #pragma unroll
    for (int i = 0; i < 4; ++i)
      #pragma unroll
      for (int j = 0; j < 4; ++j) {
        acc[i][j] = __builtin_amdgcn_mfma_f32_16x16x32_bf16(ah[i], bh[j],  acc[i][j], 0, 0, 0);
        acc[i][j] = __builtin_amdgcn_mfma_f32_16x16x32_bf16(ah[i], blo[j], acc[i][j], 0, 0, 0);
        if (!ex)
          acc[i][j] = __builtin_amdgcn_mfma_f32_16x16x32_bf16(al[i], bh[j], acc[i][j], 0, 0, 0);
      }
  }
  float blv[4];
  #pragma unroll
  for (int j = 0; j < 4; ++j) blv[j] = bias[blk * 128 + wo + j * 16 + cl];
  __syncthreads();
  // park D+bias: D[row=q*4+r][col=cl] per 16x16 tile
  #pragma unroll
  for (int i = 0; i < 4; ++i)
    #pragma unroll
    for (int j = 0; j < 4; ++j)
      #pragma unroll
      for (int r = 0; r < 4; ++r)
        ys[(wm + i * 16 + q * 4 + r) * 132 + wo + j * 16 + cl] = acc[i][j][r] + blv[j];
  __syncthreads();
  // LN: thread -> (token m = t>>1, half = t&1 covering 64 channels)
  int m = t >> 1, half = t & 1;
  const float* yr = ys + (size_t)m * 132 + half * 64;
  float s = 0.f, q2 = 0.f;
  #pragma unroll
  for (int jj = 0; jj < 16; ++jj) {
    float4 v = *(const float4*)(yr + jj * 4);
    s  += v.x + v.y + v.z + v.w;
    q2 += v.x * v.x + v.y * v.y + v.z * v.z + v.w * v.w;
  }
  s  += __shfl_xor(s, 1);
  q2 += __shfl_xor(q2, 1);
  float mean = s * (1.f / 128.f);
  float var = fmaxf(q2 * (1.f / 128.f) - mean * mean, 0.f);
  float rstd = rsqrtf(var + 1e-6f);
  #pragma unroll
  for (int jj = 0; jj < 16; ++jj) {
    int c = half * 64 + jj * 4;
    float4 v = *(const float4*)(yr + jj * 4);
    float4 g = *(const float4*)(gam + blk * 128 + c);
    float4 e = *(const float4*)(bet + blk * 128 + c);
    float4 r;
    r.x = (v.x - mean) * rstd * g.x + e.x;
    r.y = (v.y - mean) * rstd * g.y + e.y;
    r.z = (v.z - mean) * rstd * g.z + e.z;
    r.w = (v.w - mean) * rstd * g.w + e.w;
    if (DOGELU) { r.x = gelu(r.x); r.y = gelu(r.y); r.z = gelu(r.z); r.w = gelu(r.w); }
    *(float4*)(out + (tok0 + m) * 128 + c) = r;
  }
}

// ---- depthwise 3x3x3 + bias + LN + GELU. 256 thr: (cq 32) x (zg 8), 2 z each. ----
__global__ __launch_bounds__(256) void k_dw_ln(
    const float* __restrict__ in, float* __restrict__ out,
    const float* __restrict__ W, const float* __restrict__ bias,
    const float* __restrict__ gam, const float* __restrict__ bet, int blk) {
  __shared__ __align__(16) float ls[9][16][128];   // 73,728 B
  __shared__ __align__(16) float dww[27][128];     // 13,824 B
  int t = threadIdx.x;
  int xg = blockIdx.x & 15, yg = (blockIdx.x >> 4) & 15, b = blockIdx.x >> 8;
  const float* base = in + (((size_t)b) << 12) * 128;
  const float* Wb = W + (size_t)blk * 3456;
  for (int idx = t; idx < 3456; idx += 256) {
    int tap = idx >> 7, c = idx & 127;
    dww[tap][c] = Wb[c * 27 + tap];
  }
  {
    int c4 = (t & 31) * 4, zz = t >> 5;   // zz 0..7
    for (int col = 0; col < 9; ++col) {
      int yy = yg + col / 3 - 1, xx = xg + col % 3 - 1;
      bool ok = ((unsigned)yy < 16u) && ((unsigned)xx < 16u);
      #pragma unroll
      for (int w = 0; w < 2; ++w) {
        int z = zz * 2 + w;
        float4 v = {0.f, 0.f, 0.f, 0.f};
        if (ok) v = *(const float4*)(base + ((size_t)((z << 8) | (yy << 4) | xx)) * 128 + c4);
        *(float4*)&ls[col][z][c4] = v;
      }
    }
  }
  __syncthreads();
  int q = t & 31, zg = t >> 5;            // zg 0..7, each covers z = 2zg, 2zg+1
  int c0 = q * 4;
  float4 bias4 = *(const float4*)(bias + blk * 128 + c0);
  float acc[2][4];
  #pragma unroll
  for (int z4 = 0; z4 < 2; ++z4) {
    acc[z4][0] = bias4.x; acc[z4][1] = bias4.y; acc[z4][2] = bias4.z; acc[z4][3] = bias4.w;
  }
  #pragma unroll
  for (int ky = 0; ky < 3; ++ky) {
    #pragma unroll
    for (int kx = 0; kx < 3; ++kx) {
      int col = ky * 3 + kx;
      float4 cv[4];
      #pragma unroll
      for (int zz = 0; zz < 4; ++zz) {
        int z = zg * 2 + zz - 1;
        if ((unsigned)z < 16u) cv[zz] = *(const float4*)&ls[col][z][c0];
        else                   cv[zz] = {0.f, 0.f, 0.f, 0.f};
      }
      #pragma unroll
      for (int kz = 0; kz < 3; ++kz) {
        float4 w4 = *(const float4*)&dww[kz * 9 + col][c0];
        #pragma unroll
        for (int z4 = 0; z4 < 2; ++z4) {
          float4 v = cv[z4 + kz];
          acc[z4][0] += w4.x * v.x;
          acc[z4][1] += w4.y * v.y;
          acc[z4][2] += w4.z * v.z;
          acc[z4][3] += w4.w * v.w;
        }
      }
    }
  }
  float4 g4 = *(const float4*)(gam + blk * 128 + c0);
  float4 e4 = *(const float4*)(bet + blk * 128 + c0);
  #pragma unroll
  for (int z4 = 0; z4 < 2; ++z4) {
    float s  = acc[z4][0] + acc[z4][1] + acc[z4][2] + acc[z4][3];
    float qq = acc[z4][0] * acc[z4][0] + acc[z4][1] * acc[z4][1]
             + acc[z4][2] * acc[z4][2] + acc[z4][3] * acc[z4][3];
    #pragma unroll
    for (int off = 16; off; off >>= 1) {
      s  += __shfl_down(s, off, 32);
      qq += __shfl_down(qq, off, 32);
    }
    s = __shfl(s, 0, 32); qq = __shfl(qq, 0, 32);
    float mean = s * (1.f / 128.f);
    float var = fmaxf(qq * (1.f / 128.f) - mean * mean, 0.f);
    float rstd = rsqrtf(var + 1e-6f);
    int z = zg * 2 + z4;
    float4 r;
    r.x = gelu((acc[z4][0] - mean) * rstd * g4.x + e4.x);
    r.y = gelu((acc[z4][1] - mean) * rstd * g4.y + e4.y);
    r.z = gelu((acc[z4][2] - mean) * rstd * g4.z + e4.z);
    r.w = gelu((acc[z4][3] - mean) * rstd * g4.w + e4.w);
    *(float4*)(out + (((size_t)b << 12) | (z << 8) | (yg << 4) | xg) * 128 + c0) = r;
  }
}

// attn[b,c,ki*128+k] += sum_l q[b,l,c]*K[b,l,k]. 16 l-splits (chunk 256), 4+4 blocking.
__global__ __launch_bounds__(256) void k_qk(
    const float* __restrict__ qtok, const float* __restrict__ ktok,
    float* __restrict__ attn, int ki) {
  __shared__ __align__(16) float qs[32][128];
  __shared__ __align__(16) float ks[32][128];
  int ls = blockIdx.x, b = blockIdx.y;
  const float* qb = qtok + (size_t)b * ((size_t)L * C);
  const float* kb = ktok + (size_t)b * ((size_t)L * C);
  int t = threadIdx.x;
  int tc = t & 15, tk = t >> 4;
  float acc[8][8];
  #pragma unroll
  for (int i = 0; i < 8; ++i)
    #pragma unroll
    for (int j = 0; j < 8; ++j) acc[i][j] = 0.f;
  for (int l0 = ls * 256; l0 < ls * 256 + 256; l0 += 32) {
    #pragma unroll
    for (int p = 0; p < 4; ++p) {
      int idx = p * 256 + t;
      int r = idx >> 5, c4 = (idx & 31) * 4;
      *(float4*)&qs[r][c4] = *(const float4*)&qb[(size_t)(l0 + r) * 128 + c4];
      *(float4*)&ks[r][c4] = *(const float4*)&kb[(size_t)(l0 + r) * 128 + c4];
    }
    __syncthreads();
    #pragma unroll 4
    for (int l = 0; l < 32; ++l) {
      float4 q0 = *(const float4*)&qs[l][tc * 4];
      float4 q1 = *(const float4*)&qs[l][tc * 4 + 64];
      float4 k0 = *(const float4*)&ks[l][tk * 4];
      float4 k1 = *(const float4*)&ks[l][tk * 4 + 64];
      float a[8]  = {q0.x, q0.y, q0.z, q0.w, q1.x, q1.y, q1.z, q1.w};
      float bb[8] = {k0.x, k0.y, k0.z, k0.w, k1.x, k1.y, k1.z, k1.w};
      #pragma unroll
      for (int i = 0; i < 8; ++i)
        #pragma unroll
        for (int j = 0; j < 8; ++j) acc[i][j] += a[i] * bb[j];
    }
    __syncthreads();
  }
  #pragma unroll
  for (int ih = 0; ih < 2; ++ih)
    #pragma unroll
    for (int i = 0; i < 4; ++i) {
      int c = tc * 4 + ih * 64 + i;
      #pragma unroll
      for (int jh = 0; jh < 2; ++jh)
        #pragma unroll
        for (int j = 0; j < 4; ++j) {
          int kk = ki * 128 + tk * 4 + jh * 64 + j;
          atomicAdd(&attn[((size_t)b * 128 + c) * 512 + kk], acc[ih * 4 + i][jh * 4 + j]);
        }
    }
}

// masked softmax over k=512 per (b,c) row; scale = 1/64.
__global__ __launch_bounds__(128) void k_sm(float* __restrict__ attn, const int* __restrict__ mask) {
  __shared__ float rm[2], rs[2];
  int b = blockIdx.x >> 7;
  float* row = attn + (size_t)blockIdx.x * 512;
  int t = threadIdx.x;
  float v[4];
  #pragma unroll
  for (int j = 0; j < 4; ++j) {
    int k = t + j * 128;
    v[j] = (mask[b * 4 + j] > 0) ? row[k] * 0.015625f : -1e30f;
  }
  float m = fmaxf(fmaxf(v[0], v[1]), fmaxf(v[2], v[3]));
  #pragma unroll
  for (int off = 32; off; off >>= 1) m = fmaxf(m, __shfl_down(m, off));
  if ((t & 63) == 0) rm[t >> 6] = m;
  __syncthreads();
  m = fmaxf(rm[0], rm[1]);
  float e[4], s = 0.f;
  #pragma unroll
  for (int j = 0; j < 4; ++j) { e[j] = expf(v[j] - m); s += e[j]; }
  #pragma unroll
  for (int off = 32; off; off >>= 1) s += __shfl_down(s, off);
  if ((t & 63) == 0) rs[t >> 6] = s;
  __syncthreads();
  float inv = 1.f / (rs[0] + rs[1]);
  #pragma unroll
  for (int j = 0; j < 4; ++j) row[t + j * 128] = e[j] * inv;
}

// x[b,l,c] (+)= sum_{k in ki-block} P[b,c,k] * V[b,l,k]. Tile 64l x 128c.
template <bool FIRST>
__global__ __launch_bounds__(256) void k_av(
    const float* __restrict__ attn, const float* __restrict__ vtok,
    float* __restrict__ xout, int ki) {
  __shared__ float ps[128][65];
  __shared__ float vs[64][65];
  int l0 = blockIdx.x * 64, b = blockIdx.y;
  int t = threadIdx.x;
  int tx = t & 15, ty = t >> 4;
  float acc[4][8];
  #pragma unroll
  for (int i = 0; i < 4; ++i)
    #pragma unroll
    for (int j = 0; j < 8; ++j) acc[i][j] = 0.f;
  for (int kc = 0; kc < 2; ++kc) {
    #pragma unroll
    for (int p = 0; p < 8; ++p) {
      int idx = p * 256 + t;
      int c = idx >> 4, kq = (idx & 15) * 4;
      float4 v = *(const float4*)&attn[((size_t)b * 128 + c) * 512 + ki * 128 + kc * 64 + kq];
      ps[c][kq] = v.x; ps[c][kq + 1] = v.y; ps[c][kq + 2] = v.z; ps[c][kq + 3] = v.w;
    }
    #pragma unroll
    for (int p = 0; p < 4; ++p) {
      int idx = p * 256 + t;
      int l = idx >> 4, kq = (idx & 15) * 4;
      float4 v = *(const float4*)&vtok[((size_t)b * L + l0 + l) * 128 + kc * 64 + kq];
      vs[l][kq] = v.x; vs[l][kq + 1] = v.y; vs[l][kq + 2] = v.z; vs[l][kq + 3] = v.w;
    }
    __syncthreads();
    #pragma unroll 4
    for (int k = 0; k < 64; ++k) {
      float pv[8], vv[4];
      #pragma unroll
      for (int j = 0; j < 4; ++j) {
        pv[j]     = ps[tx * 4 + j][k];
        pv[j + 4] = ps[tx * 4 + 64 + j][k];
      }
      #pragma unroll
      for (int i = 0; i < 4; ++i) vv[i] = vs[ty * 4 + i][k];
      #pragma unroll
      for (int i = 0; i < 4; ++i)
        #pragma unroll
        for (int j = 0; j < 8; ++j) acc[i][j] += vv[i] * pv[j];
    }
    __syncthreads();
  }
  #pragma unroll
  for (int i = 0; i < 4; ++i) {
    float* xr = xout + ((size_t)b * L + l0 + ty * 4 + i) * 128;
    float4* p0 = (float4*)(xr + tx * 4);
    float4* p1 = (float4*)(xr + tx * 4 + 64);
    float4 o0, o1;
    if (FIRST) { o0 = {0.f, 0.f, 0.f, 0.f}; o1 = {0.f, 0.f, 0.f, 0.f}; }
    else       { o0 = *p0; o1 = *p1; }
    o0.x += acc[i][0]; o0.y += acc[i][1]; o0.z += acc[i][2]; o0.w += acc[i][3];
    o1.x += acc[i][4]; o1.y += acc[i][5]; o1.z += acc[i][6]; o1.w += acc[i][7];
    *p0 = o0; *p1 = o1;
  }
}

// out[b,c,l] = query[b,c,l] + x9[b,l,c]
__global__ __launch_bounds__(256) void k_final(
    const void* __restrict__ qv, const float* __restrict__ xin, void* __restrict__ outv,
    const int* __restrict__ flagp) {
  __shared__ float tl[32][33];
  bool isb = (*flagp != 0);
  int l0 = blockIdx.x * 32, c0 = blockIdx.y * 32, b = blockIdx.z;
  int t = threadIdx.x;
  int cc = t & 31, lr = t >> 5;
  #pragma unroll
  for (int p = 0; p < 4; ++p) {
    int l = l0 + lr + p * 8;
    tl[lr + p * 8][cc] = xin[((((size_t)b) << 12) + l) * 128 + c0 + cc];
  }
  __syncthreads();
  int lw = t & 31, cr = t >> 5;
  #pragma unroll
  for (int p = 0; p < 4; ++p) {
    int c = c0 + cr + p * 8;
    size_t idx = (((size_t)b * 128 + c) << 12) + l0 + lw;
    float qf = isb ? b2f(((const bf16*)qv)[idx]) : ((const float*)qv)[idx];
    float r = qf + tl[lw][cr + p * 8];
    if (isb) ((bf16*)outv)[idx] = f2b(r);
    else     ((float*)outv)[idx] = r;
  }
}

extern "C" void kernel_launch(void* const* d_in, const int* in_sizes, int n_in,
                              void* d_out, int out_size, void* d_ws, size_t ws_size,
                              hipStream_t stream) {
  const void* vols[5] = {d_in[0], d_in[1], d_in[2], d_in[3], d_in[4]};
  const int* mask = (const int*)d_in[5];

  char* ws = (char*)d_ws;
  int*   flag  = (int*)(ws + OFF_FLAG);
  float* wts   = (float*)(ws + OFF_WTS);
  bf16*  whi1  = (bf16*)(ws + OFF_WHI1);
  bf16*  wlo1  = (bf16*)(ws + OFF_WLO1);
  bf16*  whi2  = (bf16*)(ws + OFF_WHI2);
  bf16*  wlo2  = (bf16*)(ws + OFF_WLO2);
  float* bufA  = (float*)(ws + OFF_A);
  float* bufB  = (float*)(ws + OFF_BB);
  float* qtok  = (float*)(ws + OFF_Q);
  float* kv    = (float*)(ws + OFF_KV);
  float* xattn = (float*)(ws + OFF_X);
  float* attn  = (float*)(ws + OFF_ATT);

  k_sniff<<<1, 64, 0, stream>>>((const unsigned*)d_in[0], flag);

  const size_t woff[12] = {W_PW1, W_PW1B, W_LN1G, W_LN1B, W_DWW, W_DWB,
                           W_LN2G, W_LN2B, W_PW2, W_PW2B, W_LN3G, W_LN3B};
  for (int i = 0; i < 12; ++i) {
    int n = in_sizes[6 + i];
    if (i == 0)
      k_cvtw<<<(n + 255) / 256, 256, 0, stream>>>(d_in[6 + i], wts + woff[i], whi1, wlo1, n, flag);
    else if (i == 8)
      k_cvtw<<<(n + 255) / 256, 256, 0, stream>>>(d_in[6 + i], wts + woff[i], whi2, wlo2, n, flag);
    else
      k_cvt<<<(n + 255) / 256, 256, 0, stream>>>(d_in[6 + i], wts + woff[i], n, flag);
  }
  const float *pw1_b = wts + W_PW1B, *ln1_g = wts + W_LN1G, *ln1_b = wts + W_LN1B;
  const float *dw_w = wts + W_DWW, *dw_b = wts + W_DWB, *ln2_g = wts + W_LN2G, *ln2_b = wts + W_LN2B;
  const float *pw2_b = wts + W_PW2B, *ln3_g = wts + W_LN3G, *ln3_b = wts + W_LN3B;

  dim3 tg(L / 32, 4, 8);
  auto run_block = [&](const void* src_vol, int blk, float* dst) {
    k_transpose<<<tg, 256, 0, stream>>>(src_vol, bufA, flag);
    k_pw_mfma<true, true><<<256, 256, 0, stream>>>(bufA, bufB, whi1, wlo1, pw1_b, ln1_g, ln1_b, blk, flag);
    k_dw_ln<<<2048, 256, 0, stream>>>(bufB, bufA, dw_w, dw_b, ln2_g, ln2_b, blk);
    k_pw_mfma<false, false><<<256, 256, 0, stream>>>(bufA, dst, whi2, wlo2, pw2_b, ln3_g, ln3_b, blk, flag);
  };

  run_block(vols[0], 0, qtok);

  hipMemsetAsync(attn, 0, (size_t)B * 128 * 512 * 4, stream);

  for (int m = 1; m <= 4; ++m) {
    run_block(vols[m], m, kv);
    k_qk<<<dim3(16, 8), 256, 0, stream>>>(qtok, kv, attn, m - 1);
  }

  k_sm<<<(int)(B * 128), 128, 0, stream>>>(attn, mask);

  for (int m = 1; m <= 4; ++m) {
    run_block(vols[m], 4 + m, kv);
    if (m == 1) k_av<true><<<dim3(64, 8), 256, 0, stream>>>(attn, kv, xattn, m - 1);
    else        k_av<false><<<dim3(64, 8), 256, 0, stream>>>(attn, kv, xattn, m - 1);
  }

  k_pw_mfma<true, false><<<256, 256, 0, stream>>>(xattn, bufB, whi1, wlo1, pw1_b, ln1_g, ln1_b, 9, flag);
  k_dw_ln<<<2048, 256, 0, stream>>>(bufB, bufA, dw_w, dw_b, ln2_g, ln2_b, 9);
  k_pw_mfma<false, false><<<256, 256, 0, stream>>>(bufA, kv, whi2, wlo2, pw2_b, ln3_g, ln3_b, 9, flag);
  k_final<<<dim3(L / 32, 4, 8), 256, 0, stream>>>(vols[0], kv, d_out, flag);
}

// Round 9
// 1534.721 us; speedup vs baseline: 4.0857x; 1.0823x over previous
//
#include <hip/hip_runtime.h>
#include <hip/hip_bf16.h>

typedef __hip_bfloat16 bf16;
#define DEV __device__ __forceinline__

DEV float b2f(bf16 x) { return __bfloat162float(x); }
DEV bf16  f2b(float x) { return __float2bfloat16(x); }

typedef __attribute__((ext_vector_type(8))) short short8;   // 8 bf16 (4 VGPRs)
typedef __attribute__((ext_vector_type(4))) float f32x4;

static constexpr int B = 8, C = 128, S = 16;
static constexpr int L = S * S * S;                 // 4096
static constexpr size_t BL   = (size_t)B * L;       // 32768 tokens
static constexpr size_t VOLE = BL * C;              // 4,194,304 elements / volume

// ---- canonical f32 weight region (element offsets) ----
static constexpr size_t W_PW1  = 0;
static constexpr size_t W_PW1B = 163840;
static constexpr size_t W_LN1G = 165120;
static constexpr size_t W_LN1B = 166400;
static constexpr size_t W_DWW  = 167680;
static constexpr size_t W_DWB  = 202240;
static constexpr size_t W_LN2G = 203520;
static constexpr size_t W_LN2B = 204800;
static constexpr size_t W_PW2  = 206080;
static constexpr size_t W_PW2B = 369920;
static constexpr size_t W_LN3G = 371200;
static constexpr size_t W_LN3B = 372480;

// ---- workspace layout (bytes). ~132 MB. ----
static constexpr size_t OFF_FLAG = 0;
static constexpr size_t OFF_WTS  = 256;                     // f32 canonical weights (1.5 MB)
static constexpr size_t OFF_WHI1 = 1572864;                 // bf16 pw1_w hi
static constexpr size_t OFF_WLO1 = OFF_WHI1 + 327680;
static constexpr size_t OFF_WHI2 = OFF_WLO1 + 327680;
static constexpr size_t OFF_WLO2 = OFF_WHI2 + 327680;
static constexpr size_t OFF_A    = 4u << 20;                // f32 [B,L,C]
static constexpr size_t OFF_BB   = OFF_A  + VOLE * 4;       // f32 [B,L,C]
static constexpr size_t OFF_X    = OFF_BB + VOLE * 4;       // f32 [B,L,C] attention out
static constexpr size_t OFF_ATT  = OFF_X  + VOLE * 4;       // f32 [B,128,512]
static constexpr size_t OFF_QT   = OFF_ATT + (size_t)B * 128 * 512 * 4; // bf16 [B,C,L]
static constexpr size_t OFF_KT   = OFF_QT + VOLE * 2;       // bf16 [4][B,C,L]
static constexpr size_t OFF_VB   = OFF_KT + VOLE * 8;       // bf16 [4][B,L,C]
// end = OFF_VB + VOLE*8  ~= 132 MB

DEV float gelu(float x) { return 0.5f * x * (1.f + erff(x * 0.70710678118654752f)); }

// ---- dtype sniffer: flag=1 if inputs are bf16, 0 if f32. ----
__global__ void k_sniff(const unsigned* __restrict__ q, int* __restrict__ flag) {
  int t = threadIdx.x;
  unsigned u = q[t];
  int good = 0;
  #pragma unroll
  for (int h = 0; h < 2; ++h) {
    unsigned hb = (h ? (u & 0xffff0000u) : (u << 16));
    float v = __uint_as_float(hb);
    float a = fabsf(v);
    if (v == 0.f || (a > 1e-20f && a < 100.f)) good++;
  }
  #pragma unroll
  for (int off = 32; off; off >>= 1) good += __shfl_down(good, off);
  if (t == 0) *flag = (good >= 112) ? 1 : 0;
}

__global__ void k_cvt(const void* __restrict__ src, float* __restrict__ dst, int n,
                      const int* __restrict__ flagp) {
  int i = blockIdx.x * 256 + threadIdx.x;
  if (i >= n) return;
  if (*flagp) dst[i] = b2f(((const bf16*)src)[i]);
  else        dst[i] = ((const float*)src)[i];
}

// weights for MFMA pw: f32 canonical + bf16 hi/lo split
__global__ void k_cvtw(const void* __restrict__ src, float* __restrict__ dst,
                       bf16* __restrict__ dhi, bf16* __restrict__ dlo, int n,
                       const int* __restrict__ flagp) {
  int i = blockIdx.x * 256 + threadIdx.x;
  if (i >= n) return;
  float v = (*flagp) ? b2f(((const bf16*)src)[i]) : ((const float*)src)[i];
  dst[i] = v;
  bf16 h = f2b(v);
  dhi[i] = h;
  dlo[i] = f2b(v - b2f(h));
}

// [B,C,L] -> [B,L,C] for ONE volume, LDS-tiled, dtype-branched loads, f32 out.
__global__ __launch_bounds__(256) void k_transpose(const void* __restrict__ sv,
                                                   float* __restrict__ d,
                                                   const int* __restrict__ flagp) {
  __shared__ float t[32][33];
  bool isb = (*flagp != 0);
  int b = blockIdx.z;
  int c0 = blockIdx.y * 32, l0 = blockIdx.x * 32;
  int tid = threadIdx.x;
  int lr = tid & 31, cr = tid >> 5;
  #pragma unroll
  for (int i = 0; i < 4; ++i) {
    size_t si = ((size_t)b * C + (c0 + cr + i * 8)) * L + l0 + lr;
    t[cr + i * 8][lr] = isb ? b2f(((const bf16*)sv)[si]) : ((const float*)sv)[si];
  }
  __syncthreads();
  int cw = tid & 31, lw = tid >> 5;
  #pragma unroll
  for (int i = 0; i < 4; ++i) {
    int l = l0 + lw + i * 8;
    d[((size_t)b * L + l) * C + c0 + cw] = t[cw][lw + i * 8];
  }
}

// f32 [B,L,C] -> bf16 [B,C,L] (for q^T / K^T MFMA operands)
__global__ __launch_bounds__(256) void k_t2b(const float* __restrict__ src,
                                             bf16* __restrict__ dst) {
  __shared__ float tl[32][33];
  int l0 = blockIdx.x * 32, c0 = blockIdx.y * 32, b = blockIdx.z;
  int t = threadIdx.x;
  int cc = t & 31, lr = t >> 5;
  #pragma unroll
  for (int p = 0; p < 4; ++p) {
    int l = l0 + lr + p * 8;
    tl[lr + p * 8][cc] = src[(((size_t)b << 12) + l) * 128 + c0 + cc];
  }
  __syncthreads();
  int lw = t & 31, cr = t >> 5;
  #pragma unroll
  for (int p = 0; p < 4; ++p) {
    int c = c0 + cr + p * 8;
    dst[((size_t)b * 128 + c) * 4096 + l0 + lw] = f2b(tl[lw][cr + p * 8]);
  }
}

// f32 [B,L,C] -> bf16 [B,L,C] cast (for V MFMA operand)
__global__ __launch_bounds__(256) void k_castv(const float* __restrict__ src,
                                               bf16* __restrict__ dst) {
  size_t idx = ((size_t)blockIdx.x * 256 + threadIdx.x) * 4;
  float4 v = *(const float4*)(src + idx);
  bf16 o[4] = {f2b(v.x), f2b(v.y), f2b(v.z), f2b(v.w)};
  *(ushort4*)(dst + idx) = *(ushort4*)o;
}

// ---- pointwise conv via split-precision MFMA (hi/lo bf16) + bias+LN(+GELU). ----
template <bool DOGELU, bool XEXACT>
__global__ __launch_bounds__(256) void k_pw_mfma(
    const float* __restrict__ in, float* __restrict__ out,
    const bf16* __restrict__ Whi, const bf16* __restrict__ Wlo,
    const float* __restrict__ bias,
    const float* __restrict__ gam, const float* __restrict__ bet, int blk,
    const int* __restrict__ flagp) {
  __shared__ __align__(16) char smem[128 * 136 * 2 * 2];   // 69,632 B
  bf16* xh = (bf16*)smem;
  bf16* xl = (bf16*)(smem + 128 * 136 * 2);
  float* ys = (float*)smem;
  int t = threadIdx.x;
  bool ex = XEXACT && (*flagp != 0);
  size_t tok0 = (size_t)blockIdx.x * 128;
  const bf16* Wh = Whi + ((size_t)blk << 14);
  const bf16* Wl = Wlo + ((size_t)blk << 14);
  #pragma unroll
  for (int p = 0; p < 16; ++p) {
    int idx = p * 256 + t;
    int m = idx >> 5, c4 = (idx & 31) * 4;
    float4 v = *(const float4*)(in + (tok0 + m) * 128 + c4);
    bf16 hi[4] = {f2b(v.x), f2b(v.y), f2b(v.z), f2b(v.w)};
    *(ushort4*)(xh + m * 136 + c4) = *(ushort4*)hi;
    if (!ex) {
      bf16 lo[4] = {f2b(v.x - b2f(hi[0])), f2b(v.y - b2f(hi[1])),
                    f2b(v.z - b2f(hi[2])), f2b(v.w - b2f(hi[3]))};
      *(ushort4*)(xl + m * 136 + c4) = *(ushort4*)lo;
    }
  }
  __syncthreads();
  int w = t >> 6, lane = t & 63;
  int wm = (w >> 1) * 64, wo = (w & 1) * 64;
  int cl = lane & 15, q = lane >> 4;
  f32x4 acc[4][4] = {};
  #pragma unroll
  for (int ks = 0; ks < 4; ++ks) {
    int k = ks * 32 + q * 8;
    short8 ah[4], al[4], bh[4], blo[4];
    #pragma unroll
    for (int i = 0; i < 4; ++i) {
      ah[i] = *(const short8*)(xh + (wm + i * 16 + cl) * 136 + k);
      if (!ex) al[i] = *(const short8*)(xl + (wm + i * 16 + cl) * 136 + k);
    }
    #pragma unroll
    for (int j = 0; j < 4; ++j) {
      size_t wi = (size_t)(wo + j * 16 + cl) * 128 + k;
      bh[j]  = *(const short8*)(Wh + wi);
      blo[j] = *(const short8*)(Wl + wi);
    }
    #pragma unroll
    for (int i = 0; i < 4; ++i)
      #pragma unroll
      for (int j = 0; j < 4; ++j) {
        acc[i][j] = __builtin_amdgcn_mfma_f32_16x16x32_bf16(ah[i], bh[j],  acc[i][j], 0, 0, 0);
        acc[i][j] = __builtin_amdgcn_mfma_f32_16x16x32_bf16(ah[i], blo[j], acc[i][j], 0, 0, 0);
        if (!ex)
          acc[i][j] = __builtin_amdgcn_mfma_f32_16x16x32_bf16(al[i], bh[j], acc[i][j], 0, 0, 0);
      }
  }
  float blv[4];
  #pragma unroll
  for (int j = 0; j < 4; ++j) blv[j] = bias[blk * 128 + wo + j * 16 + cl];
  __syncthreads();
  #pragma unroll
  for (int i = 0; i < 4; ++i)
    #pragma unroll
    for (int j = 0; j < 4; ++j)
      #pragma unroll
      for (int r = 0; r < 4; ++r)
        ys[(wm + i * 16 + q * 4 + r) * 132 + wo + j * 16 + cl] = acc[i][j][r] + blv[j];
  __syncthreads();
  int m = t >> 1, half = t & 1;
  const float* yr = ys + (size_t)m * 132 + half * 64;
  float s = 0.f, q2 = 0.f;
  #pragma unroll
  for (int jj = 0; jj < 16; ++jj) {
    float4 v = *(const float4*)(yr + jj * 4);
    s  += v.x + v.y + v.z + v.w;
    q2 += v.x * v.x + v.y * v.y + v.z * v.z + v.w * v.w;
  }
  s  += __shfl_xor(s, 1);
  q2 += __shfl_xor(q2, 1);
  float mean = s * (1.f / 128.f);
  float var = fmaxf(q2 * (1.f / 128.f) - mean * mean, 0.f);
  float rstd = rsqrtf(var + 1e-6f);
  #pragma unroll
  for (int jj = 0; jj < 16; ++jj) {
    int c = half * 64 + jj * 4;
    float4 v = *(const float4*)(yr + jj * 4);
    float4 g = *(const float4*)(gam + blk * 128 + c);
    float4 e = *(const float4*)(bet + blk * 128 + c);
    float4 r;
    r.x = (v.x - mean) * rstd * g.x + e.x;
    r.y = (v.y - mean) * rstd * g.y + e.y;
    r.z = (v.z - mean) * rstd * g.z + e.z;
    r.w = (v.w - mean) * rstd * g.w + e.w;
    if (DOGELU) { r.x = gelu(r.x); r.y = gelu(r.y); r.z = gelu(r.z); r.w = gelu(r.w); }
    *(float4*)(out + (tok0 + m) * 128 + c) = r;
  }
}

// ---- depthwise 3x3x3 + bias + LN + GELU. 256 thr: (cq 32) x (zg 8). ----
__global__ __launch_bounds__(256) void k_dw_ln(
    const float* __restrict__ in, float* __restrict__ out,
    const float* __restrict__ W, const float* __restrict__ bias,
    const float* __restrict__ gam, const float* __restrict__ bet, int blk) {
  __shared__ __align__(16) float ls[9][16][128];
  __shared__ __align__(16) float dww[27][128];
  int t = threadIdx.x;
  int xg = blockIdx.x & 15, yg = (blockIdx.x >> 4) & 15, b = blockIdx.x >> 8;
  const float* base = in + (((size_t)b) << 12) * 128;
  const float* Wb = W + (size_t)blk * 3456;
  for (int idx = t; idx < 3456; idx += 256) {
    int tap = idx >> 7, c = idx & 127;
    dww[tap][c] = Wb[c * 27 + tap];
  }
  {
    int c4 = (t & 31) * 4, zz = t >> 5;
    for (int col = 0; col < 9; ++col) {
      int yy = yg + col / 3 - 1, xx = xg + col % 3 - 1;
      bool ok = ((unsigned)yy < 16u) && ((unsigned)xx < 16u);
      #pragma unroll
      for (int w = 0; w < 2; ++w) {
        int z = zz * 2 + w;
        float4 v = {0.f, 0.f, 0.f, 0.f};
        if (ok) v = *(const float4*)(base + ((size_t)((z << 8) | (yy << 4) | xx)) * 128 + c4);
        *(float4*)&ls[col][z][c4] = v;
      }
    }
  }
  __syncthreads();
  int q = t & 31, zg = t >> 5;
  int c0 = q * 4;
  float4 bias4 = *(const float4*)(bias + blk * 128 + c0);
  float acc[2][4];
  #pragma unroll
  for (int z4 = 0; z4 < 2; ++z4) {
    acc[z4][0] = bias4.x; acc[z4][1] = bias4.y; acc[z4][2] = bias4.z; acc[z4][3] = bias4.w;
  }
  #pragma unroll
  for (int ky = 0; ky < 3; ++ky) {
    #pragma unroll
    for (int kx = 0; kx < 3; ++kx) {
      int col = ky * 3 + kx;
      float4 cv[4];
      #pragma unroll
      for (int zz = 0; zz < 4; ++zz) {
        int z = zg * 2 + zz - 1;
        if ((unsigned)z < 16u) cv[zz] = *(const float4*)&ls[col][z][c0];
        else                   cv[zz] = {0.f, 0.f, 0.f, 0.f};
      }
      #pragma unroll
      for (int kz = 0; kz < 3; ++kz) {
        float4 w4 = *(const float4*)&dww[kz * 9 + col][c0];
        #pragma unroll
        for (int z4 = 0; z4 < 2; ++z4) {
          float4 v = cv[z4 + kz];
          acc[z4][0] += w4.x * v.x;
          acc[z4][1] += w4.y * v.y;
          acc[z4][2] += w4.z * v.z;
          acc[z4][3] += w4.w * v.w;
        }
      }
    }
  }
  float4 g4 = *(const float4*)(gam + blk * 128 + c0);
  float4 e4 = *(const float4*)(bet + blk * 128 + c0);
  #pragma unroll
  for (int z4 = 0; z4 < 2; ++z4) {
    float s  = acc[z4][0] + acc[z4][1] + acc[z4][2] + acc[z4][3];
    float qq = acc[z4][0] * acc[z4][0] + acc[z4][1] * acc[z4][1]
             + acc[z4][2] * acc[z4][2] + acc[z4][3] * acc[z4][3];
    #pragma unroll
    for (int off = 16; off; off >>= 1) {
      s  += __shfl_down(s, off, 32);
      qq += __shfl_down(qq, off, 32);
    }
    s = __shfl(s, 0, 32); qq = __shfl(qq, 0, 32);
    float mean = s * (1.f / 128.f);
    float var = fmaxf(qq * (1.f / 128.f) - mean * mean, 0.f);
    float rstd = rsqrtf(var + 1e-6f);
    int z = zg * 2 + z4;
    float4 r;
    r.x = gelu((acc[z4][0] - mean) * rstd * g4.x + e4.x);
    r.y = gelu((acc[z4][1] - mean) * rstd * g4.y + e4.y);
    r.z = gelu((acc[z4][2] - mean) * rstd * g4.z + e4.z);
    r.w = gelu((acc[z4][3] - mean) * rstd * g4.w + e4.w);
    *(float4*)(out + (((size_t)b << 12) | (z << 8) | (yg << 4) | xg) * 128 + c0) = r;
  }
}

// ---- qk via MFMA: attn[b,c,ki*128+k] += sum_l qT[b,c,l]*kT[ki,b,k,l]. ----
// grid (8 l-splits, 4 ki, 8 b); block 256 (4 waves, 64x64 quadrants).
__global__ __launch_bounds__(256) void k_qk_mfma(
    const bf16* __restrict__ qT, const bf16* __restrict__ kT,
    float* __restrict__ attn) {
  __shared__ __align__(16) bf16 qs[128 * 72];   // [c][64 l], stride 72
  __shared__ __align__(16) bf16 ks[128 * 72];   // [k][64 l]
  int ls = blockIdx.x, ki = blockIdx.y, b = blockIdx.z;
  const bf16* qb = qT + ((size_t)b * 128) * 4096;
  const bf16* kb = kT + (((size_t)ki * 8 + b) * 128) * 4096;
  int t = threadIdx.x;
  int w = t >> 6, lane = t & 63;
  int wm = (w >> 1) * 64, wo = (w & 1) * 64;
  int cl = lane & 15, q = lane >> 4;
  f32x4 acc[4][4] = {};
  for (int lc = 0; lc < 8; ++lc) {
    int l0 = ls * 512 + lc * 64;
    #pragma unroll
    for (int p = 0; p < 4; ++p) {
      int idx = p * 256 + t;
      int r = idx >> 3, l8 = (idx & 7) * 8;
      *(uint4*)(qs + r * 72 + l8) = *(const uint4*)(qb + (size_t)r * 4096 + l0 + l8);
      *(uint4*)(ks + r * 72 + l8) = *(const uint4*)(kb + (size_t)r * 4096 + l0 + l8);
    }
    __syncthreads();
    #pragma unroll
    for (int kstep = 0; kstep < 2; ++kstep) {
      int kk = kstep * 32 + q * 8;
      short8 a[4], bb[4];
      #pragma unroll
      for (int i = 0; i < 4; ++i) a[i]  = *(const short8*)(qs + (wm + i * 16 + cl) * 72 + kk);
      #pragma unroll
      for (int j = 0; j < 4; ++j) bb[j] = *(const short8*)(ks + (wo + j * 16 + cl) * 72 + kk);
      #pragma unroll
      for (int i = 0; i < 4; ++i)
        #pragma unroll
        for (int j = 0; j < 4; ++j)
          acc[i][j] = __builtin_amdgcn_mfma_f32_16x16x32_bf16(a[i], bb[j], acc[i][j], 0, 0, 0);
    }
    __syncthreads();
  }
  #pragma unroll
  for (int i = 0; i < 4; ++i)
    #pragma unroll
    for (int j = 0; j < 4; ++j)
      #pragma unroll
      for (int r = 0; r < 4; ++r) {
        int c = wm + i * 16 + q * 4 + r;
        int k = ki * 128 + wo + j * 16 + cl;
        atomicAdd(&attn[((size_t)b * 128 + c) * 512 + k], acc[i][j][r]);
      }
}

// masked softmax over k=512 per (b,c) row; scale = 1/64.
__global__ __launch_bounds__(128) void k_sm(float* __restrict__ attn, const int* __restrict__ mask) {
  __shared__ float rm[2], rs[2];
  int b = blockIdx.x >> 7;
  float* row = attn + (size_t)blockIdx.x * 512;
  int t = threadIdx.x;
  float v[4];
  #pragma unroll
  for (int j = 0; j < 4; ++j) {
    int k = t + j * 128;
    v[j] = (mask[b * 4 + j] > 0) ? row[k] * 0.015625f : -1e30f;
  }
  float m = fmaxf(fmaxf(v[0], v[1]), fmaxf(v[2], v[3]));
  #pragma unroll
  for (int off = 32; off; off >>= 1) m = fmaxf(m, __shfl_down(m, off));
  if ((t & 63) == 0) rm[t >> 6] = m;
  __syncthreads();
  m = fmaxf(rm[0], rm[1]);
  float e[4], s = 0.f;
  #pragma unroll
  for (int j = 0; j < 4; ++j) { e[j] = expf(v[j] - m); s += e[j]; }
  #pragma unroll
  for (int off = 32; off; off >>= 1) s += __shfl_down(s, off);
  if ((t & 63) == 0) rs[t >> 6] = s;
  __syncthreads();
  float inv = 1.f / (rs[0] + rs[1]);
  #pragma unroll
  for (int j = 0; j < 4; ++j) row[t + j * 128] = e[j] * inv;
}

// ---- av via MFMA: x[b,l,c] = sum_k P[b,c,k]*V[ki,b,l,k]. Full k=512 in-block. ----
// grid (32 l-tiles, 8 b); block 256.
__global__ __launch_bounds__(256) void k_av_mfma(
    const float* __restrict__ attn, const bf16* __restrict__ vball,
    float* __restrict__ xout) {
  __shared__ __align__(16) bf16 vs[128 * 72];   // [l][64 k]
  __shared__ __align__(16) bf16 ps[128 * 72];   // [c][64 k]
  int lt = blockIdx.x, b = blockIdx.y;
  int t = threadIdx.x;
  int w = t >> 6, lane = t & 63;
  int wm = (w >> 1) * 64, wo = (w & 1) * 64;    // wm: l-offset, wo: c-offset
  int cl = lane & 15, q = lane >> 4;
  f32x4 acc[4][4] = {};
  for (int ki = 0; ki < 4; ++ki) {
    const bf16* vbp = vball + (((size_t)ki * 8 + b) * L) * 128;
    for (int kc = 0; kc < 2; ++kc) {
      #pragma unroll
      for (int p = 0; p < 4; ++p) {
        int idx = p * 256 + t;
        int r = idx >> 3, k8 = (idx & 7) * 8;
        *(uint4*)(vs + r * 72 + k8) =
            *(const uint4*)(vbp + (size_t)(lt * 128 + r) * 128 + kc * 64 + k8);
      }
      #pragma unroll
      for (int p = 0; p < 8; ++p) {
        int idx = p * 256 + t;
        int c = idx >> 4, k4 = (idx & 15) * 4;
        float4 v = *(const float4*)&attn[((size_t)b * 128 + c) * 512 + ki * 128 + kc * 64 + k4];
        bf16 o[4] = {f2b(v.x), f2b(v.y), f2b(v.z), f2b(v.w)};
        *(ushort4*)(ps + c * 72 + k4) = *(ushort4*)o;
      }
      __syncthreads();
      #pragma unroll
      for (int kstep = 0; kstep < 2; ++kstep) {
        int kk = kstep * 32 + q * 8;
        short8 a[4], bb[4];
        #pragma unroll
        for (int i = 0; i < 4; ++i) a[i]  = *(const short8*)(vs + (wm + i * 16 + cl) * 72 + kk);
        #pragma unroll
        for (int j = 0; j < 4; ++j) bb[j] = *(const short8*)(ps + (wo + j * 16 + cl) * 72 + kk);
        #pragma unroll
        for (int i = 0; i < 4; ++i)
          #pragma unroll
          for (int j = 0; j < 4; ++j)
            acc[i][j] = __builtin_amdgcn_mfma_f32_16x16x32_bf16(a[i], bb[j], acc[i][j], 0, 0, 0);
      }
      __syncthreads();
    }
  }
  #pragma unroll
  for (int i = 0; i < 4; ++i)
    #pragma unroll
    for (int j = 0; j < 4; ++j)
      #pragma unroll
      for (int r = 0; r < 4; ++r) {
        int l = lt * 128 + wm + i * 16 + q * 4 + r;
        int c = wo + j * 16 + cl;
        xout[((size_t)b * L + l) * 128 + c] = acc[i][j][r];
      }
}

// out[b,c,l] = query[b,c,l] + x9[b,l,c]
__global__ __launch_bounds__(256) void k_final(
    const void* __restrict__ qv, const float* __restrict__ xin, void* __restrict__ outv,
    const int* __restrict__ flagp) {
  __shared__ float tl[32][33];
  bool isb = (*flagp != 0);
  int l0 = blockIdx.x * 32, c0 = blockIdx.y * 32, b = blockIdx.z;
  int t = threadIdx.x;
  int cc = t & 31, lr = t >> 5;
  #pragma unroll
  for (int p = 0; p < 4; ++p) {
    int l = l0 + lr + p * 8;
    tl[lr + p * 8][cc] = xin[((((size_t)b) << 12) + l) * 128 + c0 + cc];
  }
  __syncthreads();
  int lw = t & 31, cr = t >> 5;
  #pragma unroll
  for (int p = 0; p < 4; ++p) {
    int c = c0 + cr + p * 8;
    size_t idx = (((size_t)b * 128 + c) << 12) + l0 + lw;
    float qf = isb ? b2f(((const bf16*)qv)[idx]) : ((const float*)qv)[idx];
    float r = qf + tl[lw][cr + p * 8];
    if (isb) ((bf16*)outv)[idx] = f2b(r);
    else     ((float*)outv)[idx] = r;
  }
}

extern "C" void kernel_launch(void* const* d_in, const int* in_sizes, int n_in,
                              void* d_out, int out_size, void* d_ws, size_t ws_size,
                              hipStream_t stream) {
  const void* vols[5] = {d_in[0], d_in[1], d_in[2], d_in[3], d_in[4]};
  const int* mask = (const int*)d_in[5];

  char* ws = (char*)d_ws;
  int*   flag  = (int*)(ws + OFF_FLAG);
  float* wts   = (float*)(ws + OFF_WTS);
  bf16*  whi1  = (bf16*)(ws + OFF_WHI1);
  bf16*  wlo1  = (bf16*)(ws + OFF_WLO1);
  bf16*  whi2  = (bf16*)(ws + OFF_WHI2);
  bf16*  wlo2  = (bf16*)(ws + OFF_WLO2);
  float* bufA  = (float*)(ws + OFF_A);
  float* bufB  = (float*)(ws + OFF_BB);
  float* xattn = (float*)(ws + OFF_X);
  float* attn  = (float*)(ws + OFF_ATT);
  bf16*  qT    = (bf16*)(ws + OFF_QT);
  bf16*  kT    = (bf16*)(ws + OFF_KT);
  bf16*  vb    = (bf16*)(ws + OFF_VB);

  k_sniff<<<1, 64, 0, stream>>>((const unsigned*)d_in[0], flag);

  const size_t woff[12] = {W_PW1, W_PW1B, W_LN1G, W_LN1B, W_DWW, W_DWB,
                           W_LN2G, W_LN2B, W_PW2, W_PW2B, W_LN3G, W_LN3B};
  for (int i = 0; i < 12; ++i) {
    int n = in_sizes[6 + i];
    if (i == 0)
      k_cvtw<<<(n + 255) / 256, 256, 0, stream>>>(d_in[6 + i], wts + woff[i], whi1, wlo1, n, flag);
    else if (i == 8)
      k_cvtw<<<(n + 255) / 256, 256, 0, stream>>>(d_in[6 + i], wts + woff[i], whi2, wlo2, n, flag);
    else
      k_cvt<<<(n + 255) / 256, 256, 0, stream>>>(d_in[6 + i], wts + woff[i], n, flag);
  }
  const float *pw1_b = wts + W_PW1B, *ln1_g = wts + W_LN1G, *ln1_b = wts + W_LN1B;
  const float *dw_w = wts + W_DWW, *dw_b = wts + W_DWB, *ln2_g = wts + W_LN2G, *ln2_b = wts + W_LN2B;
  const float *pw2_b = wts + W_PW2B, *ln3_g = wts + W_LN3G, *ln3_b = wts + W_LN3B;

  dim3 tg(L / 32, 4, 8);
  // transpose->A; pw1 A->B; dw B->A; pw2 A->B (result in bufB f32)
  auto run_block = [&](const void* src_vol, int blk) {
    k_transpose<<<tg, 256, 0, stream>>>(src_vol, bufA, flag);
    k_pw_mfma<true, true><<<256, 256, 0, stream>>>(bufA, bufB, whi1, wlo1, pw1_b, ln1_g, ln1_b, blk, flag);
    k_dw_ln<<<2048, 256, 0, stream>>>(bufB, bufA, dw_w, dw_b, ln2_g, ln2_b, blk);
    k_pw_mfma<false, false><<<256, 256, 0, stream>>>(bufA, bufB, whi2, wlo2, pw2_b, ln3_g, ln3_b, blk, flag);
  };

  // q stream (block 0) -> qT bf16 [c][l]
  run_block(vols[0], 0);
  k_t2b<<<tg, 256, 0, stream>>>(bufB, qT);

  hipMemsetAsync(attn, 0, (size_t)B * 128 * 512 * 4, stream);

  // K streams (blocks 1-4) -> kT bf16 [k][l]
  for (int m = 1; m <= 4; ++m) {
    run_block(vols[m], m);
    k_t2b<<<tg, 256, 0, stream>>>(bufB, kT + (size_t)(m - 1) * VOLE);
  }

  // single qk dispatch over all ki
  k_qk_mfma<<<dim3(8, 4, 8), 256, 0, stream>>>(qT, kT, attn);
  k_sm<<<(int)(B * 128), 128, 0, stream>>>(attn, mask);

  // V streams (blocks 5-8) -> vb bf16 [l][k]
  for (int m = 1; m <= 4; ++m) {
    run_block(vols[m], 4 + m);
    k_castv<<<(int)(VOLE / 1024), 256, 0, stream>>>(bufB, vb + (size_t)(m - 1) * VOLE);
  }

  // single av dispatch, writes xattn directly (no memset needed)
  k_av_mfma<<<dim3(32, 8), 256, 0, stream>>>(attn, vb, xattn);

  // block 9 on attention output, then residual + transpose back
  k_pw_mfma<true, false><<<256, 256, 0, stream>>>(xattn, bufB, whi1, wlo1, pw1_b, ln1_g, ln1_b, 9, flag);
  k_dw_ln<<<2048, 256, 0, stream>>>(bufB, bufA, dw_w, dw_b, ln2_g, ln2_b, 9);
  k_pw_mfma<false, false><<<256, 256, 0, stream>>>(bufA, bufB, whi2, wlo2, pw2_b, ln3_g, ln3_b, 9, flag);
  k_final<<<dim3(L / 32, 4, 8), 256, 0, stream>>>(vols[0], bufB, d_out, flag);
}

// Round 10
// 1098.342 us; speedup vs baseline: 5.7090x; 1.3973x over previous
//
#include <hip/hip_runtime.h>
#include <hip/hip_bf16.h>

typedef __hip_bfloat16 bf16;
#define DEV __device__ __forceinline__

DEV float b2f(bf16 x) { return __bfloat162float(x); }
DEV bf16  f2b(float x) { return __float2bfloat16(x); }

typedef __attribute__((ext_vector_type(8))) short short8;   // 8 bf16 (4 VGPRs)
typedef __attribute__((ext_vector_type(4))) float f32x4;

static constexpr int B = 8, C = 128, S = 16;
static constexpr int L = S * S * S;                 // 4096
static constexpr size_t BL   = (size_t)B * L;       // 32768 tokens
static constexpr size_t VOLE = BL * C;              // 4,194,304 elements / volume

// ---- canonical f32 weight region (element offsets) ----
static constexpr size_t W_PW1  = 0;
static constexpr size_t W_PW1B = 163840;
static constexpr size_t W_LN1G = 165120;
static constexpr size_t W_LN1B = 166400;
static constexpr size_t W_DWW  = 167680;
static constexpr size_t W_DWB  = 202240;
static constexpr size_t W_LN2G = 203520;
static constexpr size_t W_LN2B = 204800;
static constexpr size_t W_PW2  = 206080;
static constexpr size_t W_PW2B = 369920;
static constexpr size_t W_LN3G = 371200;
static constexpr size_t W_LN3B = 372480;

// ---- workspace layout (bytes). ~142 MB. ----
static constexpr size_t OFF_FLAG = 0;
static constexpr size_t OFF_WTS  = 256;
static constexpr size_t OFF_WHI1 = 1572864;
static constexpr size_t OFF_WLO1 = OFF_WHI1 + 327680;
static constexpr size_t OFF_WHI2 = OFF_WLO1 + 327680;
static constexpr size_t OFF_WLO2 = OFF_WHI2 + 327680;
static constexpr size_t OFF_T    = 4u << 20;                // f32 [B,L,C] transposed vol (persist)
static constexpr size_t OFF_A    = OFF_T  + VOLE * 4;       // f32 chain temp
static constexpr size_t OFF_BB   = OFF_A  + VOLE * 4;       // f32 chain temp
static constexpr size_t OFF_X    = OFF_BB + VOLE * 4;       // f32 attention out
static constexpr size_t OFF_ATT  = OFF_X  + VOLE * 4;       // f32 [B,128,512]
static constexpr size_t OFF_QT   = OFF_ATT + (size_t)B * 128 * 512 * 4; // bf16 [B,C,L]
static constexpr size_t OFF_KT   = OFF_QT + VOLE * 2;       // bf16 [4][B,C,L]
static constexpr size_t OFF_VB   = OFF_KT + VOLE * 8;       // bf16 [4][B,L,C]

DEV float gelu(float x) { return 0.5f * x * (1.f + erff(x * 0.70710678118654752f)); }

__global__ void k_sniff(const unsigned* __restrict__ q, int* __restrict__ flag) {
  int t = threadIdx.x;
  unsigned u = q[t];
  int good = 0;
  #pragma unroll
  for (int h = 0; h < 2; ++h) {
    unsigned hb = (h ? (u & 0xffff0000u) : (u << 16));
    float v = __uint_as_float(hb);
    float a = fabsf(v);
    if (v == 0.f || (a > 1e-20f && a < 100.f)) good++;
  }
  #pragma unroll
  for (int off = 32; off; off >>= 1) good += __shfl_down(good, off);
  if (t == 0) *flag = (good >= 112) ? 1 : 0;
}

__global__ void k_cvt(const void* __restrict__ src, float* __restrict__ dst, int n,
                      const int* __restrict__ flagp) {
  int i = blockIdx.x * 256 + threadIdx.x;
  if (i >= n) return;
  if (*flagp) dst[i] = b2f(((const bf16*)src)[i]);
  else        dst[i] = ((const float*)src)[i];
}

__global__ void k_cvtw(const void* __restrict__ src, float* __restrict__ dst,
                       bf16* __restrict__ dhi, bf16* __restrict__ dlo, int n,
                       const int* __restrict__ flagp) {
  int i = blockIdx.x * 256 + threadIdx.x;
  if (i >= n) return;
  float v = (*flagp) ? b2f(((const bf16*)src)[i]) : ((const float*)src)[i];
  dst[i] = v;
  bf16 h = f2b(v);
  dhi[i] = h;
  dlo[i] = f2b(v - b2f(h));
}

// [B,C,L] -> [B,L,C] for ONE volume, LDS-tiled, dtype-branched loads, f32 out.
__global__ __launch_bounds__(256) void k_transpose(const void* __restrict__ sv,
                                                   float* __restrict__ d,
                                                   const int* __restrict__ flagp) {
  __shared__ float t[32][33];
  bool isb = (*flagp != 0);
  int b = blockIdx.z;
  int c0 = blockIdx.y * 32, l0 = blockIdx.x * 32;
  int tid = threadIdx.x;
  int lr = tid & 31, cr = tid >> 5;
  #pragma unroll
  for (int i = 0; i < 4; ++i) {
    size_t si = ((size_t)b * C + (c0 + cr + i * 8)) * L + l0 + lr;
    t[cr + i * 8][lr] = isb ? b2f(((const bf16*)sv)[si]) : ((const float*)sv)[si];
  }
  __syncthreads();
  int cw = tid & 31, lw = tid >> 5;
  #pragma unroll
  for (int i = 0; i < 4; ++i) {
    int l = l0 + lw + i * 8;
    d[((size_t)b * L + l) * C + c0 + cw] = t[cw][lw + i * 8];
  }
}

// ---- pointwise conv via split-precision MFMA + fused bias+LN(+GELU) + fused output cast. ----
// Tile 64 tokens x 128 outputs, 256 thr (4 waves), grid 512. LDS 34.8 KB -> 4 blocks/CU cap.
// OUTMODE: 0 = f32 [l][c], 1 = bf16 [l][c], 2 = bf16 [c][l] (transposed, for q/K).
template <bool DOGELU, bool XEXACT, int OUTMODE>
__global__ __launch_bounds__(256) void k_pw_mfma(
    const float* __restrict__ in, void* __restrict__ outv,
    const bf16* __restrict__ Whi, const bf16* __restrict__ Wlo,
    const float* __restrict__ bias,
    const float* __restrict__ gam, const float* __restrict__ bet, int blk,
    const int* __restrict__ flagp) {
  __shared__ __align__(16) char smem[64 * 136 * 2 * 2];   // 34,816 B
  bf16* xh = (bf16*)smem;                                 // [64][136]
  bf16* xl = (bf16*)(smem + 64 * 136 * 2);
  float* ys = (float*)smem;                               // [64][133] = 34,048 B (alias)
  int t = threadIdx.x;
  bool ex = XEXACT && (*flagp != 0);
  size_t tok0 = (size_t)blockIdx.x * 64;
  const bf16* Wh = Whi + ((size_t)blk << 14);
  const bf16* Wl = Wlo + ((size_t)blk << 14);
  // stage x hi/lo: 64 tokens x 128 ch
  #pragma unroll
  for (int p = 0; p < 8; ++p) {
    int idx = p * 256 + t;
    int m = idx >> 5, c4 = (idx & 31) * 4;
    float4 v = *(const float4*)(in + (tok0 + m) * 128 + c4);
    bf16 hi[4] = {f2b(v.x), f2b(v.y), f2b(v.z), f2b(v.w)};
    *(ushort4*)(xh + m * 136 + c4) = *(ushort4*)hi;
    if (!ex) {
      bf16 lo[4] = {f2b(v.x - b2f(hi[0])), f2b(v.y - b2f(hi[1])),
                    f2b(v.z - b2f(hi[2])), f2b(v.w - b2f(hi[3]))};
      *(ushort4*)(xl + m * 136 + c4) = *(ushort4*)lo;
    }
  }
  __syncthreads();
  int w = t >> 6, lane = t & 63;
  int wm = (w & 1) * 32, wo = (w >> 1) * 64;   // wave: 32 tokens x 64 outputs
  int cl = lane & 15, q = lane >> 4;
  f32x4 acc[2][4] = {};
  #pragma unroll
  for (int ks = 0; ks < 4; ++ks) {
    int k = ks * 32 + q * 8;
    short8 ah[2], al[2], bh[4], blo[4];
    #pragma unroll
    for (int i = 0; i < 2; ++i) {
      ah[i] = *(const short8*)(xh + (wm + i * 16 + cl) * 136 + k);
      if (!ex) al[i] = *(const short8*)(xl + (wm + i * 16 + cl) * 136 + k);
    }
    #pragma unroll
    for (int j = 0; j < 4; ++j) {
      size_t wi = (size_t)(wo + j * 16 + cl) * 128 + k;
      bh[j]  = *(const short8*)(Wh + wi);
      blo[j] = *(const short8*)(Wl + wi);
    }
    #pragma unroll
    for (int i = 0; i < 2; ++i)
      #pragma unroll
      for (int j = 0; j < 4; ++j) {
        acc[i][j] = __builtin_amdgcn_mfma_f32_16x16x32_bf16(ah[i], bh[j],  acc[i][j], 0, 0, 0);
        acc[i][j] = __builtin_amdgcn_mfma_f32_16x16x32_bf16(ah[i], blo[j], acc[i][j], 0, 0, 0);
        if (!ex)
          acc[i][j] = __builtin_amdgcn_mfma_f32_16x16x32_bf16(al[i], bh[j], acc[i][j], 0, 0, 0);
      }
  }
  float blv[4];
  #pragma unroll
  for (int j = 0; j < 4; ++j) blv[j] = bias[blk * 128 + wo + j * 16 + cl];
  __syncthreads();
  // park D+bias into ys[64][133]
  #pragma unroll
  for (int i = 0; i < 2; ++i)
    #pragma unroll
    for (int j = 0; j < 4; ++j)
      #pragma unroll
      for (int r = 0; r < 4; ++r)
        ys[(wm + i * 16 + q * 4 + r) * 133 + wo + j * 16 + cl] = acc[i][j][r] + blv[j];
  __syncthreads();
  // LN: 4 threads per token, each 32 channels
  int m = t >> 2, qtr = t & 3;
  float* yr = ys + (size_t)m * 133 + qtr * 32;
  float s = 0.f, q2 = 0.f;
  #pragma unroll
  for (int jj = 0; jj < 8; ++jj) {
    float4 v = *(const float4*)(yr + jj * 4);
    s  += v.x + v.y + v.z + v.w;
    q2 += v.x * v.x + v.y * v.y + v.z * v.z + v.w * v.w;
  }
  s += __shfl_xor(s, 1);  q2 += __shfl_xor(q2, 1);
  s += __shfl_xor(s, 2);  q2 += __shfl_xor(q2, 2);
  float mean = s * (1.f / 128.f);
  float var = fmaxf(q2 * (1.f / 128.f) - mean * mean, 0.f);
  float rstd = rsqrtf(var + 1e-6f);
  #pragma unroll
  for (int jj = 0; jj < 8; ++jj) {
    int c = qtr * 32 + jj * 4;
    float4 v = *(const float4*)(yr + jj * 4);
    float4 g = *(const float4*)(gam + blk * 128 + c);
    float4 e = *(const float4*)(bet + blk * 128 + c);
    float4 r;
    r.x = (v.x - mean) * rstd * g.x + e.x;
    r.y = (v.y - mean) * rstd * g.y + e.y;
    r.z = (v.z - mean) * rstd * g.z + e.z;
    r.w = (v.w - mean) * rstd * g.w + e.w;
    if (DOGELU) { r.x = gelu(r.x); r.y = gelu(r.y); r.z = gelu(r.z); r.w = gelu(r.w); }
    if (OUTMODE == 0) {
      *(float4*)((float*)outv + (tok0 + m) * 128 + c) = r;
    } else if (OUTMODE == 1) {
      bf16 o[4] = {f2b(r.x), f2b(r.y), f2b(r.z), f2b(r.w)};
      *(ushort4*)((bf16*)outv + (tok0 + m) * 128 + c) = *(ushort4*)o;
    } else {
      *(float4*)(yr + jj * 4) = r;   // write back for transposed pass
    }
  }
  if (OUTMODE == 2) {
    __syncthreads();
    // transposed store: out[b*128+c][l0 + l], 2 threads per c (32 l each)
    int b = (int)(tok0 >> 12), l0 = (int)(tok0 & 4095);
    int c = t >> 1, lh = (t & 1) * 32;
    bf16 tmp[32];
    #pragma unroll
    for (int i = 0; i < 32; ++i) tmp[i] = f2b(ys[(size_t)(lh + i) * 133 + c]);
    bf16* dst = (bf16*)outv + ((size_t)b * 128 + c) * 4096 + l0 + lh;
    #pragma unroll
    for (int i = 0; i < 4; ++i) *(uint4*)(dst + i * 8) = *(uint4*)(tmp + i * 8);
  }
}

// ---- depthwise 3x3x3 + bias + LN + GELU. 512 thr: (cq 32) x (zg 16), 1 z each. ----
__global__ __launch_bounds__(512) void k_dw_ln(
    const float* __restrict__ in, float* __restrict__ out,
    const float* __restrict__ W, const float* __restrict__ bias,
    const float* __restrict__ gam, const float* __restrict__ bet, int blk) {
  __shared__ __align__(16) float ls[9][16][128];   // 73,728 B
  __shared__ __align__(16) float dww[27][128];     // 13,824 B
  int t = threadIdx.x;
  int xg = blockIdx.x & 15, yg = (blockIdx.x >> 4) & 15, b = blockIdx.x >> 8;
  const float* base = in + (((size_t)b) << 12) * 128;
  const float* Wb = W + (size_t)blk * 3456;
  for (int idx = t; idx < 3456; idx += 512) {
    int tap = idx >> 7, c = idx & 127;
    dww[tap][c] = Wb[c * 27 + tap];
  }
  {
    int c4 = (t & 31) * 4, zz = t >> 5;   // zz 0..15
    for (int col = 0; col < 9; ++col) {
      int yy = yg + col / 3 - 1, xx = xg + col % 3 - 1;
      bool ok = ((unsigned)yy < 16u) && ((unsigned)xx < 16u);
      float4 v = {0.f, 0.f, 0.f, 0.f};
      if (ok) v = *(const float4*)(base + ((size_t)((zz << 8) | (yy << 4) | xx)) * 128 + c4);
      *(float4*)&ls[col][zz][c4] = v;
    }
  }
  __syncthreads();
  int q = t & 31, zg = t >> 5;   // zg 0..15 = z
  int c0 = q * 4;
  float4 bias4 = *(const float4*)(bias + blk * 128 + c0);
  float acc[4] = {bias4.x, bias4.y, bias4.z, bias4.w};
  #pragma unroll
  for (int ky = 0; ky < 3; ++ky) {
    #pragma unroll
    for (int kx = 0; kx < 3; ++kx) {
      int col = ky * 3 + kx;
      #pragma unroll
      for (int kz = 0; kz < 3; ++kz) {
        int z = zg + kz - 1;
        float4 v = {0.f, 0.f, 0.f, 0.f};
        if ((unsigned)z < 16u) v = *(const float4*)&ls[col][z][c0];
        float4 w4 = *(const float4*)&dww[kz * 9 + col][c0];
        acc[0] += w4.x * v.x;
        acc[1] += w4.y * v.y;
        acc[2] += w4.z * v.z;
        acc[3] += w4.w * v.w;
      }
    }
  }
  float4 g4 = *(const float4*)(gam + blk * 128 + c0);
  float4 e4 = *(const float4*)(bet + blk * 128 + c0);
  float s  = acc[0] + acc[1] + acc[2] + acc[3];
  float qq = acc[0] * acc[0] + acc[1] * acc[1] + acc[2] * acc[2] + acc[3] * acc[3];
  #pragma unroll
  for (int off = 16; off; off >>= 1) {
    s  += __shfl_down(s, off, 32);
    qq += __shfl_down(qq, off, 32);
  }
  s = __shfl(s, 0, 32); qq = __shfl(qq, 0, 32);
  float mean = s * (1.f / 128.f);
  float var = fmaxf(qq * (1.f / 128.f) - mean * mean, 0.f);
  float rstd = rsqrtf(var + 1e-6f);
  float4 r;
  r.x = gelu((acc[0] - mean) * rstd * g4.x + e4.x);
  r.y = gelu((acc[1] - mean) * rstd * g4.y + e4.y);
  r.z = gelu((acc[2] - mean) * rstd * g4.z + e4.z);
  r.w = gelu((acc[3] - mean) * rstd * g4.w + e4.w);
  *(float4*)(out + (((size_t)b << 12) | (zg << 8) | (yg << 4) | xg) * 128 + c0) = r;
}

// ---- qk via MFMA ----
__global__ __launch_bounds__(256) void k_qk_mfma(
    const bf16* __restrict__ qT, const bf16* __restrict__ kT,
    float* __restrict__ attn) {
  __shared__ __align__(16) bf16 qs[128 * 72];
  __shared__ __align__(16) bf16 ks[128 * 72];
  int ls = blockIdx.x, ki = blockIdx.y, b = blockIdx.z;
  const bf16* qb = qT + ((size_t)b * 128) * 4096;
  const bf16* kb = kT + (((size_t)ki * 8 + b) * 128) * 4096;
  int t = threadIdx.x;
  int w = t >> 6, lane = t & 63;
  int wm = (w >> 1) * 64, wo = (w & 1) * 64;
  int cl = lane & 15, q = lane >> 4;
  f32x4 acc[4][4] = {};
  for (int lc = 0; lc < 8; ++lc) {
    int l0 = ls * 512 + lc * 64;
    #pragma unroll
    for (int p = 0; p < 4; ++p) {
      int idx = p * 256 + t;
      int r = idx >> 3, l8 = (idx & 7) * 8;
      *(uint4*)(qs + r * 72 + l8) = *(const uint4*)(qb + (size_t)r * 4096 + l0 + l8);
      *(uint4*)(ks + r * 72 + l8) = *(const uint4*)(kb + (size_t)r * 4096 + l0 + l8);
    }
    __syncthreads();
    #pragma unroll
    for (int kstep = 0; kstep < 2; ++kstep) {
      int kk = kstep * 32 + q * 8;
      short8 a[4], bb[4];
      #pragma unroll
      for (int i = 0; i < 4; ++i) a[i]  = *(const short8*)(qs + (wm + i * 16 + cl) * 72 + kk);
      #pragma unroll
      for (int j = 0; j < 4; ++j) bb[j] = *(const short8*)(ks + (wo + j * 16 + cl) * 72 + kk);
      #pragma unroll
      for (int i = 0; i < 4; ++i)
        #pragma unroll
        for (int j = 0; j < 4; ++j)
          acc[i][j] = __builtin_amdgcn_mfma_f32_16x16x32_bf16(a[i], bb[j], acc[i][j], 0, 0, 0);
    }
    __syncthreads();
  }
  #pragma unroll
  for (int i = 0; i < 4; ++i)
    #pragma unroll
    for (int j = 0; j < 4; ++j)
      #pragma unroll
      for (int r = 0; r < 4; ++r) {
        int c = wm + i * 16 + q * 4 + r;
        int k = ki * 128 + wo + j * 16 + cl;
        atomicAdd(&attn[((size_t)b * 128 + c) * 512 + k], acc[i][j][r]);
      }
}

// masked softmax over k=512 per (b,c) row; scale = 1/64.
__global__ __launch_bounds__(128) void k_sm(float* __restrict__ attn, const int* __restrict__ mask) {
  __shared__ float rm[2], rs[2];
  int b = blockIdx.x >> 7;
  float* row = attn + (size_t)blockIdx.x * 512;
  int t = threadIdx.x;
  float v[4];
  #pragma unroll
  for (int j = 0; j < 4; ++j) {
    int k = t + j * 128;
    v[j] = (mask[b * 4 + j] > 0) ? row[k] * 0.015625f : -1e30f;
  }
  float m = fmaxf(fmaxf(v[0], v[1]), fmaxf(v[2], v[3]));
  #pragma unroll
  for (int off = 32; off; off >>= 1) m = fmaxf(m, __shfl_down(m, off));
  if ((t & 63) == 0) rm[t >> 6] = m;
  __syncthreads();
  m = fmaxf(rm[0], rm[1]);
  float e[4], s = 0.f;
  #pragma unroll
  for (int j = 0; j < 4; ++j) { e[j] = expf(v[j] - m); s += e[j]; }
  #pragma unroll
  for (int off = 32; off; off >>= 1) s += __shfl_down(s, off);
  if ((t & 63) == 0) rs[t >> 6] = s;
  __syncthreads();
  float inv = 1.f / (rs[0] + rs[1]);
  #pragma unroll
  for (int j = 0; j < 4; ++j) row[t + j * 128] = e[j] * inv;
}

// ---- av via MFMA ----
__global__ __launch_bounds__(256) void k_av_mfma(
    const float* __restrict__ attn, const bf16* __restrict__ vball,
    float* __restrict__ xout) {
  __shared__ __align__(16) bf16 vs[128 * 72];
  __shared__ __align__(16) bf16 ps[128 * 72];
  int lt = blockIdx.x, b = blockIdx.y;
  int t = threadIdx.x;
  int w = t >> 6, lane = t & 63;
  int wm = (w >> 1) * 64, wo = (w & 1) * 64;
  int cl = lane & 15, q = lane >> 4;
  f32x4 acc[4][4] = {};
  for (int ki = 0; ki < 4; ++ki) {
    const bf16* vbp = vball + (((size_t)ki * 8 + b) * L) * 128;
    for (int kc = 0; kc < 2; ++kc) {
      #pragma unroll
      for (int p = 0; p < 4; ++p) {
        int idx = p * 256 + t;
        int r = idx >> 3, k8 = (idx & 7) * 8;
        *(uint4*)(vs + r * 72 + k8) =
            *(const uint4*)(vbp + (size_t)(lt * 128 + r) * 128 + kc * 64 + k8);
      }
      #pragma unroll
      for (int p = 0; p < 8; ++p) {
        int idx = p * 256 + t;
        int c = idx >> 4, k4 = (idx & 15) * 4;
        float4 v = *(const float4*)&attn[((size_t)b * 128 + c) * 512 + ki * 128 + kc * 64 + k4];
        bf16 o[4] = {f2b(v.x), f2b(v.y), f2b(v.z), f2b(v.w)};
        *(ushort4*)(ps + c * 72 + k4) = *(ushort4*)o;
      }
      __syncthreads();
      #pragma unroll
      for (int kstep = 0; kstep < 2; ++kstep) {
        int kk = kstep * 32 + q * 8;
        short8 a[4], bb[4];
        #pragma unroll
        for (int i = 0; i < 4; ++i) a[i]  = *(const short8*)(vs + (wm + i * 16 + cl) * 72 + kk);
        #pragma unroll
        for (int j = 0; j < 4; ++j) bb[j] = *(const short8*)(ps + (wo + j * 16 + cl) * 72 + kk);
        #pragma unroll
        for (int i = 0; i < 4; ++i)
          #pragma unroll
          for (int j = 0; j < 4; ++j)
            acc[i][j] = __builtin_amdgcn_mfma_f32_16x16x32_bf16(a[i], bb[j], acc[i][j], 0, 0, 0);
      }
      __syncthreads();
    }
  }
  #pragma unroll
  for (int i = 0; i < 4; ++i)
    #pragma unroll
    for (int j = 0; j < 4; ++j)
      #pragma unroll
      for (int r = 0; r < 4; ++r) {
        int l = lt * 128 + wm + i * 16 + q * 4 + r;
        int c = wo + j * 16 + cl;
        xout[((size_t)b * L + l) * 128 + c] = acc[i][j][r];
      }
}

// out[b,c,l] = query[b,c,l] + x9[b,l,c]
__global__ __launch_bounds__(256) void k_final(
    const void* __restrict__ qv, const float* __restrict__ xin, void* __restrict__ outv,
    const int* __restrict__ flagp) {
  __shared__ float tl[32][33];
  bool isb = (*flagp != 0);
  int l0 = blockIdx.x * 32, c0 = blockIdx.y * 32, b = blockIdx.z;
  int t = threadIdx.x;
  int cc = t & 31, lr = t >> 5;
  #pragma unroll
  for (int p = 0; p < 4; ++p) {
    int l = l0 + lr + p * 8;
    tl[lr + p * 8][cc] = xin[((((size_t)b) << 12) + l) * 128 + c0 + cc];
  }
  __syncthreads();
  int lw = t & 31, cr = t >> 5;
  #pragma unroll
  for (int p = 0; p < 4; ++p) {
    int c = c0 + cr + p * 8;
    size_t idx = (((size_t)b * 128 + c) << 12) + l0 + lw;
    float qf = isb ? b2f(((const bf16*)qv)[idx]) : ((const float*)qv)[idx];
    float r = qf + tl[lw][cr + p * 8];
    if (isb) ((bf16*)outv)[idx] = f2b(r);
    else     ((float*)outv)[idx] = r;
  }
}

extern "C" void kernel_launch(void* const* d_in, const int* in_sizes, int n_in,
                              void* d_out, int out_size, void* d_ws, size_t ws_size,
                              hipStream_t stream) {
  const void* vols[5] = {d_in[0], d_in[1], d_in[2], d_in[3], d_in[4]};
  const int* mask = (const int*)d_in[5];

  char* ws = (char*)d_ws;
  int*   flag  = (int*)(ws + OFF_FLAG);
  float* wts   = (float*)(ws + OFF_WTS);
  bf16*  whi1  = (bf16*)(ws + OFF_WHI1);
  bf16*  wlo1  = (bf16*)(ws + OFF_WLO1);
  bf16*  whi2  = (bf16*)(ws + OFF_WHI2);
  bf16*  wlo2  = (bf16*)(ws + OFF_WLO2);
  float* bufT  = (float*)(ws + OFF_T);
  float* bufA  = (float*)(ws + OFF_A);
  float* bufB  = (float*)(ws + OFF_BB);
  float* xattn = (float*)(ws + OFF_X);
  float* attn  = (float*)(ws + OFF_ATT);
  bf16*  qT    = (bf16*)(ws + OFF_QT);
  bf16*  kT    = (bf16*)(ws + OFF_KT);
  bf16*  vb    = (bf16*)(ws + OFF_VB);

  k_sniff<<<1, 64, 0, stream>>>((const unsigned*)d_in[0], flag);

  const size_t woff[12] = {W_PW1, W_PW1B, W_LN1G, W_LN1B, W_DWW, W_DWB,
                           W_LN2G, W_LN2B, W_PW2, W_PW2B, W_LN3G, W_LN3B};
  for (int i = 0; i < 12; ++i) {
    int n = in_sizes[6 + i];
    if (i == 0)
      k_cvtw<<<(n + 255) / 256, 256, 0, stream>>>(d_in[6 + i], wts + woff[i], whi1, wlo1, n, flag);
    else if (i == 8)
      k_cvtw<<<(n + 255) / 256, 256, 0, stream>>>(d_in[6 + i], wts + woff[i], whi2, wlo2, n, flag);
    else
      k_cvt<<<(n + 255) / 256, 256, 0, stream>>>(d_in[6 + i], wts + woff[i], n, flag);
  }
  const float *pw1_b = wts + W_PW1B, *ln1_g = wts + W_LN1G, *ln1_b = wts + W_LN1B;
  const float *dw_w = wts + W_DWW, *dw_b = wts + W_DWB, *ln2_g = wts + W_LN2G, *ln2_b = wts + W_LN2B;
  const float *pw2_b = wts + W_PW2B, *ln3_g = wts + W_LN3G, *ln3_b = wts + W_LN3B;

  dim3 tg(L / 32, 4, 8);
  hipMemsetAsync(attn, 0, (size_t)B * 128 * 512 * 4, stream);

  // chain: (bufT f32 in) -> pw1 -> bufA -> dw -> bufB -> pw2 -> dst (mode-dependent)
  auto chain = [&]<int OM>(std::integral_constant<int, OM>, const float* src, int blk, void* dst) {
    k_pw_mfma<true, true, 0><<<512, 256, 0, stream>>>(src, bufA, whi1, wlo1, pw1_b, ln1_g, ln1_b, blk, flag);
    k_dw_ln<<<2048, 512, 0, stream>>>(bufA, bufB, dw_w, dw_b, ln2_g, ln2_b, blk);
    k_pw_mfma<false, false, OM><<<512, 256, 0, stream>>>(bufB, dst, whi2, wlo2, pw2_b, ln3_g, ln3_b, blk, flag);
  };

  // q stream
  k_transpose<<<tg, 256, 0, stream>>>(vols[0], bufT, flag);
  chain(std::integral_constant<int, 2>{}, bufT, 0, qT);

  // K + V streams share one transpose per modality
  for (int m = 1; m <= 4; ++m) {
    k_transpose<<<tg, 256, 0, stream>>>(vols[m], bufT, flag);
    chain(std::integral_constant<int, 2>{}, bufT, m,     kT + (size_t)(m - 1) * VOLE);
    chain(std::integral_constant<int, 1>{}, bufT, 4 + m, vb + (size_t)(m - 1) * VOLE);
  }

  k_qk_mfma<<<dim3(8, 4, 8), 256, 0, stream>>>(qT, kT, attn);
  k_sm<<<(int)(B * 128), 128, 0, stream>>>(attn, mask);
  k_av_mfma<<<dim3(32, 8), 256, 0, stream>>>(attn, vb, xattn);

  // block 9 then residual
  k_pw_mfma<true, false, 0><<<512, 256, 0, stream>>>(xattn, bufA, whi1, wlo1, pw1_b, ln1_g, ln1_b, 9, flag);
  k_dw_ln<<<2048, 512, 0, stream>>>(bufA, bufB, dw_w, dw_b, ln2_g, ln2_b, 9);
  k_pw_mfma<false, false, 0><<<512, 256, 0, stream>>>(bufB, bufA, whi2, wlo2, pw2_b, ln3_g, ln3_b, 9, flag);
  k_final<<<dim3(L / 32, 4, 8), 256, 0, stream>>>(vols[0], bufA, d_out, flag);
}